// Round 1
// baseline (1086.847 us; speedup 1.0000x reference)
//
#include <hip/hip_runtime.h>
#include <math.h>

// Problem constants
#define NQF 10000
#define CF  256

// ---------------- pooling (2x2 mean) ----------------
__global__ __launch_bounds__(256) void pool2x2(const float* __restrict__ in, float* __restrict__ out,
                                               int h, int w, int total)
{
  int i = blockIdx.x * 256 + threadIdx.x;
  if (i >= total) return;
  int x = i % w; int r = i / w; int y = r % h; int ci = r / h;
  const float* p = in + (size_t)ci * (4 * h * w) + (size_t)(2 * y) * (2 * w) + 2 * x;
  out[i] = (p[0] + p[1] + p[2 * w] + p[2 * w + 1]) * 0.25f;
}

// ---------------- build concatenated off/attn weights ----------------
__global__ __launch_bounds__(256) void buildcat(const float* __restrict__ wo, const float* __restrict__ bo,
                                                const float* __restrict__ wa, const float* __restrict__ ba,
                                                float* __restrict__ wcat, float* __restrict__ bcat)
{
  int i = blockIdx.x * 256 + threadIdx.x;
  if (i < 256 * 288) {
    int k = i / 288, c = i % 288;
    wcat[i] = (c < 192) ? wo[k * 192 + c] : wa[k * 96 + (c - 192)];
  }
  if (i < 288) bcat[i] = (i < 192) ? bo[i] : ba[i - 192];
}

// ---------------- wcomb[l] = w_fpn[l] @ w_value ----------------
__global__ __launch_bounds__(256) void wcombk(const float* __restrict__ wfpn, const float* __restrict__ wval,
                                              float* __restrict__ wcomb)
{
  int l = blockIdx.x >> 8, i = blockIdx.x & 255, j = threadIdx.x;
  const float* a = wfpn + ((size_t)l * 256 + i) * 256;
  float acc = 0.f;
  for (int k = 0; k < 256; ++k) acc = fmaf(a[k], wval[(size_t)k * 256 + j], acc);
  wcomb[((size_t)l * 256 + i) * 256 + j] = acc;
}

// ---------------- e2[n,l] = (cams[n]+lev[l]+bfpn[l]) @ w_value + b_value ----------------
__global__ __launch_bounds__(256) void e2k(const float* __restrict__ cams, const float* __restrict__ lev,
                                           const float* __restrict__ bfpn, const float* __restrict__ wval,
                                           const float* __restrict__ bval, float* __restrict__ e2)
{
  int n = blockIdx.x / 3, l = blockIdx.x % 3, j = threadIdx.x;
  float acc = bval[j];
  for (int k = 0; k < 256; ++k) {
    float s = cams[n * 256 + k] + lev[l * 256 + k] + bfpn[l * 256 + k];
    acc = fmaf(s, wval[(size_t)k * 256 + j], acc);
  }
  e2[(size_t)blockIdx.x * 256 + j] = acc;
}

// ---------------- generic NN GEMM: C = A@B (+A2 on A) (+bias) (+resid) (relu) ----------------
// A: (M,256) row-major, B: (256,N) row-major (ldb), C: (M,N) (ldc)
__global__ __launch_bounds__(256) void gemm_nn(const float* __restrict__ A, const float* __restrict__ A2,
                                               const float* __restrict__ B, int ldb,
                                               const float* __restrict__ bias, const float* __restrict__ resid,
                                               float* __restrict__ C, int ldc, int M, int N, int relu)
{
  const int K = 256;
  __shared__ float As[16][64];
  __shared__ float Bs[16][64];
  int t = threadIdx.x;
  int row0 = blockIdx.x * 64, col0 = blockIdx.y * 64;
  int tm = t >> 4, tn = t & 15;
  float acc[4][4] = {};
  for (int k0 = 0; k0 < K; k0 += 16) {
#pragma unroll
    for (int i = 0; i < 4; ++i) {
      int idx = i * 256 + t;
      int r = idx >> 4, kk = idx & 15;
      int gr = row0 + r;
      float v = 0.f;
      if (gr < M) {
        v = A[(size_t)gr * K + k0 + kk];
        if (A2) v += A2[(size_t)gr * K + k0 + kk];
      }
      As[kk][r] = v;
    }
#pragma unroll
    for (int i = 0; i < 4; ++i) {
      int idx = i * 256 + t;
      int kk = idx >> 6, c = idx & 63;
      int gc = col0 + c;
      Bs[kk][c] = (gc < N) ? B[(size_t)(k0 + kk) * ldb + gc] : 0.f;
    }
    __syncthreads();
#pragma unroll
    for (int kk = 0; kk < 16; ++kk) {
      float4 a4 = *reinterpret_cast<const float4*>(&As[kk][tm * 4]);
      float4 b4 = *reinterpret_cast<const float4*>(&Bs[kk][tn * 4]);
      float a[4] = {a4.x, a4.y, a4.z, a4.w};
      float b[4] = {b4.x, b4.y, b4.z, b4.w};
#pragma unroll
      for (int i = 0; i < 4; ++i)
#pragma unroll
        for (int j = 0; j < 4; ++j) acc[i][j] = fmaf(a[i], b[j], acc[i][j]);
    }
    __syncthreads();
  }
#pragma unroll
  for (int i = 0; i < 4; ++i) {
    int gr = row0 + tm * 4 + i;
    if (gr >= M) continue;
#pragma unroll
    for (int j = 0; j < 4; ++j) {
      int gc = col0 + tn * 4 + j;
      if (gc >= N) continue;
      float v = acc[i][j];
      if (bias) v += bias[gc];
      if (resid) v += resid[(size_t)gr * ldc + gc];
      if (relu) v = fmaxf(v, 0.f);
      C[(size_t)gr * ldc + gc] = v;
    }
  }
}

// ---------------- value GEMM (A^T layout): v[n, lstart+pos, :] = cur_row @ wcomb_l + e2[n,l] ----------------
// cur: (6, 256, hw) for one batch. Row r of A: img=r/hw, pos=r%hw; A[r,k]=cur[img,k,pos].
__global__ __launch_bounds__(256) void gemm_val(const float* __restrict__ cur, int hw, int lstart, int level,
                                                const float* __restrict__ Bw, const float* __restrict__ e2,
                                                float* __restrict__ V, int M)
{
  const int K = 256;
  __shared__ float As[16][64];
  __shared__ float Bs[16][64];
  int t = threadIdx.x;
  int row0 = blockIdx.x * 64, col0 = blockIdx.y * 64;
  int rl = t & 63, kg = t >> 6;
  int gr = row0 + rl;
  bool arow_ok = gr < M;
  int img = 0, pos = 0;
  if (arow_ok) { img = gr / hw; pos = gr - img * hw; }
  const float* Abase = cur + (size_t)img * K * hw + pos;
  int tm = t >> 4, tn = t & 15;
  float acc[4][4] = {};
  for (int k0 = 0; k0 < K; k0 += 16) {
#pragma unroll
    for (int i = 0; i < 4; ++i) {
      int kk = kg * 4 + i;
      As[kk][rl] = arow_ok ? Abase[(size_t)(k0 + kk) * hw] : 0.f;
    }
#pragma unroll
    for (int i = 0; i < 4; ++i) {
      int idx = i * 256 + t;
      int kk = idx >> 6, c = idx & 63;
      Bs[kk][c] = Bw[(size_t)(k0 + kk) * 256 + col0 + c];
    }
    __syncthreads();
#pragma unroll
    for (int kk = 0; kk < 16; ++kk) {
      float4 a4 = *reinterpret_cast<const float4*>(&As[kk][tm * 4]);
      float4 b4 = *reinterpret_cast<const float4*>(&Bs[kk][tn * 4]);
      float a[4] = {a4.x, a4.y, a4.z, a4.w};
      float b[4] = {b4.x, b4.y, b4.z, b4.w};
#pragma unroll
      for (int i = 0; i < 4; ++i)
#pragma unroll
        for (int j = 0; j < 4; ++j) acc[i][j] = fmaf(a[i], b[j], acc[i][j]);
    }
    __syncthreads();
  }
#pragma unroll
  for (int i = 0; i < 4; ++i) {
    int r = row0 + tm * 4 + i;
    if (r >= M) continue;
    int im = r / hw, ps = r - im * hw;
    float* dst = V + ((size_t)im * 3696 + lstart + ps) * 256;
    const float* bias = e2 + (size_t)(im * 3 + level) * 256;
#pragma unroll
    for (int j = 0; j < 4; ++j) {
      int c = col0 + tn * 4 + j;
      dst[c] = acc[i][j] + bias[c];
    }
  }
}

// ---------------- deformable sampling + attention + cam-average -> slots ----------------
// qtmp: (NQ,288) = [off(192) | attn logits(96)]; V: (6,3696,256); l2i: (6,4,4) for this batch.
__global__ __launch_bounds__(256) void sca_sample(const float* __restrict__ qtmp, const float* __restrict__ V,
                                                  const float* __restrict__ l2i, float* __restrict__ slots)
{
  int q = blockIdx.x;
  int t = threadIdx.x;
  int head = t >> 5, dh = t & 31;
  __shared__ float raw[288];
  __shared__ float attn[96];
  __shared__ float refx[6][4], refy[6][4];
  __shared__ int mnd[6][4];
  __shared__ int validn[6];
  __shared__ float invcnt;

  raw[t] = qtmp[(size_t)q * 288 + t];
  if (t < 32) raw[256 + t] = qtmp[(size_t)q * 288 + 256 + t];
  if (t >= 32 && t < 56) {
    int tt = t - 32;
    int n = tt >> 2, d = tt & 3;
    const float* Mrow = l2i + n * 16;
    int qx = q % 100, qy = q / 100;
    float X = ((qx + 0.5f) / 100.0f) * 102.4f + (-51.2f);
    float Y = ((qy + 0.5f) / 100.0f) * 102.4f + (-51.2f);
    float zi = (d == 3) ? 7.5f : (0.5f + (float)d * (7.0f / 3.0f));
    float Z = (zi / 8.0f) * 8.0f + (-5.0f);
    float px = Mrow[0] * X + Mrow[1] * Y + Mrow[2] * Z + Mrow[3];
    float py = Mrow[4] * X + Mrow[5] * Y + Mrow[6] * Z + Mrow[7];
    float pz = Mrow[8] * X + Mrow[9] * Y + Mrow[10] * Z + Mrow[11];
    float dz = fmaxf(pz, 1e-5f);
    float xc = (px / dz) / 704.0f;
    float yc = (py / dz) / 256.0f;
    refx[n][d] = xc; refy[n][d] = yc;
    mnd[n][d] = (pz > 1e-5f) && (xc > 0.f) && (xc < 1.f) && (yc > 0.f) && (yc < 1.f);
  }
  __syncthreads();
  if (t < 8) {
    float mx = raw[192 + t * 12];
    for (int p = 1; p < 12; ++p) mx = fmaxf(mx, raw[192 + t * 12 + p]);
    float s = 0.f;
    for (int p = 0; p < 12; ++p) { float e = expf(raw[192 + t * 12 + p] - mx); attn[t * 12 + p] = e; s += e; }
    float inv = 1.f / s;
    for (int p = 0; p < 12; ++p) attn[t * 12 + p] *= inv;
  }
  if (t >= 8 && t < 14) {
    int n = t - 8;
    validn[n] = mnd[n][0] | mnd[n][1] | mnd[n][2] | mnd[n][3];
  }
  __syncthreads();
  if (t == 0) {
    int cnt = validn[0] + validn[1] + validn[2] + validn[3] + validn[4] + validn[5];
    invcnt = 1.0f / (float)(cnt > 1 ? cnt : 1);
  }
  __syncthreads();

  float acc = 0.f;
  const int HH[3] = {32, 16, 8}, WW[3] = {88, 44, 22}, ST[3] = {0, 2816, 3520};
  for (int n = 0; n < 6; ++n) {
    if (!validn[n]) continue;
    const float* Vn = V + (size_t)n * 3696 * 256 + head * 32 + dh;
#pragma unroll
    for (int l = 0; l < 3; ++l) {
      int hh = HH[l], ww = WW[l], st = ST[l];
#pragma unroll
      for (int d = 0; d < 4; ++d) {
        float ox = raw[head * 24 + l * 8 + d * 2 + 0];
        float oy = raw[head * 24 + l * 8 + d * 2 + 1];
        float lx = refx[n][d] + ox / (float)ww;
        float ly = refy[n][d] + oy / (float)hh;
        float x = lx * (float)ww - 0.5f;
        float y = ly * (float)hh - 0.5f;
        float x0 = floorf(x), y0 = floorf(y);
        float fx = x - x0, fy = y - y0;
        float sacc = 0.f;
#pragma unroll
        for (int dy = 0; dy < 2; ++dy) {
          float yi = y0 + (float)dy;
          if (yi < 0.f || yi >= (float)hh) continue;
          float wy = dy ? fy : 1.f - fy;
#pragma unroll
          for (int dx = 0; dx < 2; ++dx) {
            float xi = x0 + (float)dx;
            if (xi < 0.f || xi >= (float)ww) continue;
            float wx = dx ? fx : 1.f - fx;
            int idx = (int)yi * ww + (int)xi;
            sacc = fmaf(wx * wy, Vn[(size_t)(st + idx) * 256], sacc);
          }
        }
        acc = fmaf(attn[head * 12 + l * 4 + d], sacc, acc);
      }
    }
  }
  slots[(size_t)q * 256 + t] = acc * invcnt;
}

// ---------------- final output assembly ----------------
__global__ __launch_bounds__(256) void final_copy(const float* __restrict__ ego, const float* __restrict__ nb,
                                                  float* __restrict__ out)
{
  int i = blockIdx.x * 256 + threadIdx.x;
  if (i >= 2560000) return;
  float e = ego[i];
  out[i] = e;
  out[2560000 + i] = e;
  out[5120000 + i] = nb[i];
}

extern "C" void kernel_launch(void* const* d_in, const int* in_sizes, int n_in,
                              void* d_out, int out_size, void* d_ws, size_t ws_size,
                              hipStream_t stream)
{
  const float* imgs = (const float*)d_in[0];
  const float* l2i = (const float*)d_in[1];
  const float* bev_query = (const float*)d_in[2];
  const float* bev_pos = (const float*)d_in[3];
  const float* cams = (const float*)d_in[4];
  const float* lev = (const float*)d_in[5];
  const float* wfpn = (const float*)d_in[6];
  const float* bfpn = (const float*)d_in[7];
  const float* wval = (const float*)d_in[8];
  const float* bval = (const float*)d_in[9];
  const float* woff = (const float*)d_in[10];
  const float* boff = (const float*)d_in[11];
  const float* wattn = (const float*)d_in[12];
  const float* battn = (const float*)d_in[13];
  const float* wout = (const float*)d_in[14];
  const float* bout = (const float*)d_in[15];
  const float* wts1 = (const float*)d_in[16];
  const float* bts1 = (const float*)d_in[17];
  const float* wts2 = (const float*)d_in[18];
  const float* bts2 = (const float*)d_in[19];

  float* W = (float*)d_ws;
  size_t off = 0;
  auto alloc = [&](size_t n) { float* p = W + off; off += n; return p; };
  float* v = alloc((size_t)6 * 3696 * 256);    // 5,677,056
  float* cur1 = alloc((size_t)12 * 256 * 16 * 44); // 2,162,688
  float* cur2 = alloc((size_t)12 * 256 * 8 * 22);  // 540,672
  float* bqA = alloc(2560000);
  float* bqB = alloc(2560000);
  float* qtmp = alloc(2880000);  // reused as FFN temp t
  float* slots = alloc(2560000); // reused as FFN temp t1
  float* wcat = alloc(288 * 256);
  float* bcat = alloc(512);
  float* wcomb = alloc(3 * 256 * 256);
  float* e2 = alloc(18 * 256);
  (void)ws_size;

  // ---- precompute ----
  pool2x2<<<(2162688 + 255) / 256, 256, 0, stream>>>(imgs, cur1, 16, 44, 2162688);
  pool2x2<<<(540672 + 255) / 256, 256, 0, stream>>>(cur1, cur2, 8, 22, 540672);
  buildcat<<<288, 256, 0, stream>>>(woff, boff, wattn, battn, wcat, bcat);
  wcombk<<<768, 256, 0, stream>>>(wfpn, wval, wcomb);
  e2k<<<18, 256, 0, stream>>>(cams, lev, bfpn, wval, bval, e2);

  auto run_value = [&](int b) {
    gemm_val<<<dim3(264, 4), 256, 0, stream>>>(imgs + (size_t)b * 6 * 256 * 2816, 2816, 0, 0, wcomb, e2, v, 16896);
    gemm_val<<<dim3(66, 4), 256, 0, stream>>>(cur1 + (size_t)b * 6 * 256 * 704, 704, 2816, 1, wcomb + 65536, e2, v, 4224);
    gemm_val<<<dim3(17, 4), 256, 0, stream>>>(cur2 + (size_t)b * 6 * 256 * 176, 176, 3520, 2, wcomb + 131072, e2, v, 1056);
  };
  auto run_iter = [&](const float* qin, float* qout, int b) {
    // off/attn projection: (bq+pos) @ [w_off|w_attn] + [b_off|b_attn]
    gemm_nn<<<dim3(157, 5), 256, 0, stream>>>(qin, bev_pos, wcat, 288, bcat, nullptr, qtmp, 288, 10000, 288, 0);
    // deformable sampling -> slots
    sca_sample<<<10000, 256, 0, stream>>>(qtmp, v, l2i + b * 96, slots);
    // out projection + residual
    float* tbuf = qtmp;
    gemm_nn<<<dim3(157, 4), 256, 0, stream>>>(slots, nullptr, wout, 256, bout, qin, tbuf, 256, 10000, 256, 0);
    // FFN
    float* t1 = slots;
    gemm_nn<<<dim3(157, 4), 256, 0, stream>>>(tbuf, nullptr, wts1, 256, bts1, nullptr, t1, 256, 10000, 256, 1);
    gemm_nn<<<dim3(157, 4), 256, 0, stream>>>(t1, nullptr, wts2, 256, bts2, nullptr, qout, 256, 10000, 256, 0);
  };

  run_value(0);
  run_iter(bev_query, bqA, 0);
  run_iter(bqA, bqB, 0); // bqB = ego
  run_value(1);
  run_iter(bqB, bqA, 1); // bqA = nb
  final_copy<<<10000, 256, 0, stream>>>(bqB, bqA, (float*)d_out);
}

// Round 2
// 969.127 us; speedup vs baseline: 1.1215x; 1.1215x over previous
//
#include <hip/hip_runtime.h>
#include <math.h>

typedef __attribute__((ext_vector_type(8))) short bf16x8;
typedef __attribute__((ext_vector_type(4))) float f32x4;

__device__ __forceinline__ unsigned short f2bf(float x) {
  union { float f; unsigned int u; } v; v.f = x;
  unsigned int r = v.u + 0x7fffu + ((v.u >> 16) & 1u);
  return (unsigned short)(r >> 16);
}
__device__ __forceinline__ float bf2f(unsigned short b) {
  union { unsigned int u; float f; } v; v.u = ((unsigned int)b) << 16; return v.f;
}
__device__ __forceinline__ void split2(float x, unsigned short& h, unsigned short& l) {
  h = f2bf(x);
  l = f2bf(x - bf2f(h));
}

// ---------------- pooling (2x2 mean) ----------------
__global__ __launch_bounds__(256) void pool2x2(const float* __restrict__ in, float* __restrict__ out,
                                               int h, int w, int total)
{
  int i = blockIdx.x * 256 + threadIdx.x;
  if (i >= total) return;
  int x = i % w; int r = i / w; int y = r % h; int ci = r / h;
  const float* p = in + (size_t)ci * (4 * h * w) + (size_t)(2 * y) * (2 * w) + 2 * x;
  out[i] = (p[0] + p[1] + p[2 * w] + p[2 * w + 1]) * 0.25f;
}

// ---------------- build concatenated off/attn weights, transposed + split ----------------
// wcatT[c][k] (288 x 256) hi/lo, bcat[288]
__global__ __launch_bounds__(256) void buildcat(const float* __restrict__ wo, const float* __restrict__ bo,
                                                const float* __restrict__ wa, const float* __restrict__ ba,
                                                unsigned short* __restrict__ WH, unsigned short* __restrict__ WL,
                                                float* __restrict__ bcat)
{
  int i = blockIdx.x * 256 + threadIdx.x;
  if (i < 288 * 256) {
    int c = i >> 8, k = i & 255;
    float v = (c < 192) ? wo[k * 192 + c] : wa[k * 96 + (c - 192)];
    unsigned short h, l; split2(v, h, l);
    WH[i] = h; WL[i] = l;
  }
  if (i < 288) bcat[i] = (i < 192) ? bo[i] : ba[i - 192];
}

// ---------------- generic weight transpose+split: src (256,N) -> dst (N,256) hi/lo ----------------
__global__ __launch_bounds__(256) void conv_w(const float* __restrict__ B, int N,
                                              unsigned short* __restrict__ H, unsigned short* __restrict__ L)
{
  int i = blockIdx.x * 256 + threadIdx.x;
  if (i >= N * 256) return;
  int nn = i >> 8, k = i & 255;
  float v = B[(size_t)k * N + nn];
  unsigned short h, l; split2(v, h, l);
  H[i] = h; L[i] = l;
}

// ---------------- wcombT[l][n][k] = (w_fpn[l] @ w_value)^T, split ----------------
__global__ __launch_bounds__(256) void wcombk(const float* __restrict__ wfpn, const float* __restrict__ wval,
                                              unsigned short* __restrict__ WH, unsigned short* __restrict__ WL)
{
  int l = blockIdx.x >> 8, i = blockIdx.x & 255, j = threadIdx.x; // i = k(out), j = n
  const float* a = wfpn + ((size_t)l * 256 + i) * 256;
  float acc = 0.f;
  for (int k = 0; k < 256; ++k) acc = fmaf(a[k], wval[(size_t)k * 256 + j], acc);
  unsigned short h, lo; split2(acc, h, lo);
  size_t o = ((size_t)l * 256 + j) * 256 + i;
  WH[o] = h; WL[o] = lo;
}

// ---------------- e2[n,l] = (cams[n]+lev[l]+bfpn[l]) @ w_value + b_value ----------------
__global__ __launch_bounds__(256) void e2k(const float* __restrict__ cams, const float* __restrict__ lev,
                                           const float* __restrict__ bfpn, const float* __restrict__ wval,
                                           const float* __restrict__ bval, float* __restrict__ e2)
{
  int n = blockIdx.x / 3, l = blockIdx.x % 3, j = threadIdx.x;
  float acc = bval[j];
  for (int k = 0; k < 256; ++k) {
    float s = cams[n * 256 + k] + lev[l * 256 + k] + bfpn[l * 256 + k];
    acc = fmaf(s, wval[(size_t)k * 256 + j], acc);
  }
  e2[(size_t)blockIdx.x * 256 + j] = acc;
}

// ---------------- activation split: H/L = split(A [+A2]) ----------------
__global__ __launch_bounds__(256) void conv_a(const float4* __restrict__ A, const float4* __restrict__ A2,
                                              ushort4* __restrict__ H, ushort4* __restrict__ L, int n4)
{
  int i = blockIdx.x * 256 + threadIdx.x;
  if (i >= n4) return;
  float4 v = A[i];
  if (A2) { float4 w = A2[i]; v.x += w.x; v.y += w.y; v.z += w.z; v.w += w.w; }
  ushort4 hh, ll;
  split2(v.x, hh.x, ll.x); split2(v.y, hh.y, ll.y);
  split2(v.z, hh.z, ll.z); split2(v.w, hh.w, ll.w);
  H[i] = hh; L[i] = ll;
}

// ---------------- transpose+split value activations: src (6,256,hw) -> dst ((img*hw+pos),256) ----------------
__global__ __launch_bounds__(256) void conv_v(const float* __restrict__ src, int hw,
                                              unsigned short* __restrict__ H, unsigned short* __restrict__ L)
{
  __shared__ float T[32][33];
  int t = threadIdx.x;
  int img = blockIdx.z, k0 = blockIdx.y * 32, p0 = blockIdx.x * 32;
  const float* s = src + ((size_t)img * 256 + k0) * hw + p0;
#pragma unroll
  for (int r = 0; r < 4; ++r) {
    int e = r * 256 + t;
    int kk = e >> 5, pp = e & 31;
    float v = 0.f;
    if (p0 + pp < hw) v = s[(size_t)kk * hw + pp];
    T[kk][pp] = v;
  }
  __syncthreads();
#pragma unroll
  for (int r = 0; r < 4; ++r) {
    int e = r * 256 + t;
    int pp = e >> 5, kk = e & 31;
    if (p0 + pp < hw) {
      float v = T[kk][pp];
      unsigned short h, l; split2(v, h, l);
      size_t o = ((size_t)img * hw + p0 + pp) * 256 + k0 + kk;
      H[o] = h; L[o] = l;
    }
  }
}

// ---------------- split-bf16 MFMA GEMM ----------------
// A (M,256) as hi/lo bf16 row-major; Bt (N,256) hi/lo (= B^T); C = A@B.
// Tile 128x128, 4 waves (2x2), BK=32. LDS layout [hi/lo][kchunk][row][8] -> conflict-free b128 reads.
__global__ __launch_bounds__(256, 2) void gemm_mfma(
    const unsigned short* __restrict__ Ah, const unsigned short* __restrict__ Al,
    const unsigned short* __restrict__ Bh, const unsigned short* __restrict__ Bl,
    int M, int N,
    long long Az, long long Cz, int biasz,
    const float* __restrict__ bias,
    const float* __restrict__ resid,
    const float* __restrict__ posadd,
    float* __restrict__ Cf, int ldcf,
    unsigned short* __restrict__ Ch, unsigned short* __restrict__ Cl,
    int relu)
{
  __shared__ unsigned short AS[2][4][128][8];
  __shared__ unsigned short BS[2][4][128][8];

  int z = blockIdx.z;
  Ah += (size_t)z * Az; Al += (size_t)z * Az;
  if (Cf) Cf += (size_t)z * Cz;
  if (bias) bias += (size_t)z * biasz;

  int t = threadIdx.x;
  int wid = t >> 6, lane = t & 63;
  int wr = wid >> 1, wc = wid & 1;
  int r0 = blockIdx.x * 128, c0 = blockIdx.y * 128;

  // staging role: wave 0->A_hi, 1->A_lo, 2->B_hi, 3->B_lo
  const unsigned short* gsrc = (wid == 0) ? Ah : (wid == 1) ? Al : (wid == 2) ? Bh : Bl;
  unsigned short (*lds)[128][8] = (wid == 0) ? AS[0] : (wid == 1) ? AS[1] : (wid == 2) ? BS[0] : BS[1];
  int lim = (wid < 2) ? M : N;
  int base0 = (wid < 2) ? r0 : c0;

  f32x4 acc[4][4] = {};

  auto stage = [&](int ks) {
    int k0 = ks * 32;
#pragma unroll
    for (int i = 0; i < 8; ++i) {
      int c = i >> 1, half = i & 1;
      int row = base0 + half * 64 + lane;
      if (row >= lim) row = lim - 1;
      const unsigned short* ga = gsrc + (size_t)row * 256 + k0 + c * 8;
      void* dst = (void*)&lds[c][half * 64][0];
      __builtin_amdgcn_global_load_lds((const __attribute__((address_space(1))) void*)ga,
                                       (__attribute__((address_space(3))) void*)dst, 16, 0, 0);
    }
  };

  int l15 = lane & 15, lk = lane >> 4;

  stage(0);
  for (int ks = 0; ks < 8; ++ks) {
    __syncthreads();
    bf16x8 ahv[4], alv[4], bhv[4], blv[4];
#pragma unroll
    for (int mf = 0; mf < 4; ++mf) {
      int m = wr * 64 + mf * 16 + l15;
      ahv[mf] = *(const bf16x8*)(&AS[0][lk][m][0]);
      alv[mf] = *(const bf16x8*)(&AS[1][lk][m][0]);
    }
#pragma unroll
    for (int nf = 0; nf < 4; ++nf) {
      int n = wc * 64 + nf * 16 + l15;
      bhv[nf] = *(const bf16x8*)(&BS[0][lk][n][0]);
      blv[nf] = *(const bf16x8*)(&BS[1][lk][n][0]);
    }
#pragma unroll
    for (int mf = 0; mf < 4; ++mf)
#pragma unroll
      for (int nf = 0; nf < 4; ++nf) {
        acc[mf][nf] = __builtin_amdgcn_mfma_f32_16x16x32_bf16(ahv[mf], bhv[nf], acc[mf][nf], 0, 0, 0);
        acc[mf][nf] = __builtin_amdgcn_mfma_f32_16x16x32_bf16(ahv[mf], blv[nf], acc[mf][nf], 0, 0, 0);
        acc[mf][nf] = __builtin_amdgcn_mfma_f32_16x16x32_bf16(alv[mf], bhv[nf], acc[mf][nf], 0, 0, 0);
      }
    if (ks < 7) { __syncthreads(); stage(ks + 1); }
  }

  // epilogue: C/D layout col=lane&15, row=(lane>>4)*4+reg
  int lg = lane >> 4;
#pragma unroll
  for (int mf = 0; mf < 4; ++mf) {
#pragma unroll
    for (int nf = 0; nf < 4; ++nf) {
      int cidx = c0 + wc * 64 + nf * 16 + l15;
      if (cidx >= N) continue;
      int rbase = r0 + wr * 64 + mf * 16 + lg * 4;
#pragma unroll
      for (int reg = 0; reg < 4; ++reg) {
        int rr = rbase + reg;
        if (rr >= M) continue;
        float v = acc[mf][nf][reg];
        if (bias) v += bias[cidx];
        if (resid) v += resid[(size_t)rr * 256 + cidx];
        if (relu) v = fmaxf(v, 0.f);
        if (Cf) Cf[(size_t)rr * ldcf + cidx] = v;
        if (Ch) {
          float vp = posadd ? v + posadd[(size_t)rr * 256 + cidx] : v;
          unsigned short h, l; split2(vp, h, l);
          Ch[(size_t)rr * 256 + cidx] = h;
          Cl[(size_t)rr * 256 + cidx] = l;
        }
      }
    }
  }
}

// ---------------- deformable sampling + attention + cam-average -> slots ----------------
__global__ __launch_bounds__(256) void sca_sample(const float* __restrict__ qtmp, const float* __restrict__ V,
                                                  const float* __restrict__ l2i, float* __restrict__ slots)
{
  int q = blockIdx.x;
  int t = threadIdx.x;
  int head = t >> 5;
  __shared__ float raw[288];
  __shared__ float attn[96];
  __shared__ float refx[6][4], refy[6][4];
  __shared__ int mnd[24];
  __shared__ int validn[6];
  __shared__ __align__(16) float w4[576][4];
  __shared__ __align__(16) int o4[576][4];

  raw[t] = qtmp[(size_t)q * 288 + t];
  if (t < 32) raw[256 + t] = qtmp[(size_t)q * 288 + 256 + t];
  if (t >= 32 && t < 56) {
    int tt = t - 32;
    int n = tt >> 2, d = tt & 3;
    const float* Mrow = l2i + n * 16;
    int qx = q % 100, qy = q / 100;
    float X = ((qx + 0.5f) / 100.0f) * 102.4f + (-51.2f);
    float Y = ((qy + 0.5f) / 100.0f) * 102.4f + (-51.2f);
    float zi = (d == 3) ? 7.5f : (0.5f + (float)d * (7.0f / 3.0f));
    float Z = zi + (-5.0f);
    float px = Mrow[0] * X + Mrow[1] * Y + Mrow[2] * Z + Mrow[3];
    float py = Mrow[4] * X + Mrow[5] * Y + Mrow[6] * Z + Mrow[7];
    float pz = Mrow[8] * X + Mrow[9] * Y + Mrow[10] * Z + Mrow[11];
    float dz = fmaxf(pz, 1e-5f);
    float xc = (px / dz) / 704.0f;
    float yc = (py / dz) / 256.0f;
    refx[n][d] = xc; refy[n][d] = yc;
    mnd[n * 4 + d] = (pz > 1e-5f) && (xc > 0.f) && (xc < 1.f) && (yc > 0.f) && (yc < 1.f);
  }
  __syncthreads();
  if (t < 8) {
    float mx = raw[192 + t * 12];
    for (int p = 1; p < 12; ++p) mx = fmaxf(mx, raw[192 + t * 12 + p]);
    float s = 0.f;
    for (int p = 0; p < 12; ++p) { float e = expf(raw[192 + t * 12 + p] - mx); attn[t * 12 + p] = e; s += e; }
    float inv = 1.f / s;
    for (int p = 0; p < 12; ++p) attn[t * 12 + p] *= inv;
  } else if (t >= 8 && t < 14) {
    int n = t - 8;
    validn[n] = mnd[n * 4] | mnd[n * 4 + 1] | mnd[n * 4 + 2] | mnd[n * 4 + 3];
  }
  // per-point table: pt = (n*12 + l*4 + d)*8 + head
  const float WWf[3] = {88.f, 44.f, 22.f}, HHf[3] = {32.f, 16.f, 8.f};
  const int WWi[3] = {88, 44, 22}, STi[3] = {0, 2816, 3520};
  for (int pt = t; pt < 576; pt += 256) {
    int hd = pt & 7;
    int g = pt >> 3;
    int d = g & 3;
    int nl = g >> 2;
    int l = nl % 3, n = nl / 3;
    float wwf = WWf[l], hhf = HHf[l];
    int wwi = WWi[l], st = STi[l];
    float ox = raw[hd * 24 + l * 8 + d * 2 + 0];
    float oy = raw[hd * 24 + l * 8 + d * 2 + 1];
    float x = refx[n][d] * wwf + ox - 0.5f;
    float y = refy[n][d] * hhf + oy - 0.5f;
    float x0 = floorf(x), y0 = floorf(y);
    float fx = x - x0, fy = y - y0;
    float wx0 = 1.f - fx, wy0 = 1.f - fy;
    float vx0 = (x0 >= 0.f && x0 < wwf) ? 1.f : 0.f;
    float vx1 = (x0 + 1.f >= 0.f && x0 + 1.f < wwf) ? 1.f : 0.f;
    float vy0 = (y0 >= 0.f && y0 < hhf) ? 1.f : 0.f;
    float vy1 = (y0 + 1.f >= 0.f && y0 + 1.f < hhf) ? 1.f : 0.f;
    w4[pt][0] = wx0 * wy0 * vx0 * vy0;
    w4[pt][1] = fx * wy0 * vx1 * vy0;
    w4[pt][2] = wx0 * fy * vx0 * vy1;
    w4[pt][3] = fx * fy * vx1 * vy1;
    int ix0 = (int)fminf(fmaxf(x0, 0.f), wwf - 1.f);
    int ix1 = (int)fminf(fmaxf(x0 + 1.f, 0.f), wwf - 1.f);
    int iy0 = (int)fminf(fmaxf(y0, 0.f), hhf - 1.f);
    int iy1 = (int)fminf(fmaxf(y0 + 1.f, 0.f), hhf - 1.f);
    int rA = (st + iy0 * wwi) * 256, rB = (st + iy1 * wwi) * 256;
    o4[pt][0] = rA + ix0 * 256;
    o4[pt][1] = rA + ix1 * 256;
    o4[pt][2] = rB + ix0 * 256;
    o4[pt][3] = rB + ix1 * 256;
  }
  __syncthreads();

  int cnt = validn[0] + validn[1] + validn[2] + validn[3] + validn[4] + validn[5];
  float invc = 1.f / (float)(cnt > 1 ? cnt : 1);

  float acc = 0.f;
  for (int n = 0; n < 6; ++n) {
    if (!validn[n]) continue;
    const float* Vn = V + (size_t)n * 946176 + t;
    int pb = n * 96 + head;
#pragma unroll
    for (int j = 0; j < 12; ++j) {
      int pt = pb + j * 8;
      float4 w = *reinterpret_cast<const float4*>(&w4[pt][0]);
      int4 o = *reinterpret_cast<const int4*>(&o4[pt][0]);
      float a = attn[head * 12 + j];
      float s = w.x * Vn[o.x] + w.y * Vn[o.y] + w.z * Vn[o.z] + w.w * Vn[o.w];
      acc = fmaf(a, s, acc);
    }
  }
  slots[(size_t)q * 256 + t] = acc * invc;
}

// ---------------- final output assembly ----------------
__global__ __launch_bounds__(256) void final_copy(const float* __restrict__ ego, const float* __restrict__ nb,
                                                  float* __restrict__ out)
{
  int i = blockIdx.x * 256 + threadIdx.x;
  if (i >= 2560000) return;
  float e = ego[i];
  out[i] = e;
  out[2560000 + i] = e;
  out[5120000 + i] = nb[i];
}

extern "C" void kernel_launch(void* const* d_in, const int* in_sizes, int n_in,
                              void* d_out, int out_size, void* d_ws, size_t ws_size,
                              hipStream_t stream)
{
  const float* imgs = (const float*)d_in[0];
  const float* l2i = (const float*)d_in[1];
  const float* bev_query = (const float*)d_in[2];
  const float* bev_pos = (const float*)d_in[3];
  const float* cams = (const float*)d_in[4];
  const float* lev = (const float*)d_in[5];
  const float* wfpn = (const float*)d_in[6];
  const float* bfpn = (const float*)d_in[7];
  const float* wval = (const float*)d_in[8];
  const float* bval = (const float*)d_in[9];
  const float* woff = (const float*)d_in[10];
  const float* boff = (const float*)d_in[11];
  const float* wattn = (const float*)d_in[12];
  const float* battn = (const float*)d_in[13];
  const float* wout = (const float*)d_in[14];
  const float* bout = (const float*)d_in[15];
  const float* wts1 = (const float*)d_in[16];
  const float* bts1 = (const float*)d_in[17];
  const float* wts2 = (const float*)d_in[18];
  const float* bts2 = (const float*)d_in[19];

  float* W = (float*)d_ws;
  size_t off = 0;
  auto alloc = [&](size_t n) { float* p = W + off; off += n; return p; };
  float* v = alloc((size_t)6 * 3696 * 256);        // 5,677,056
  float* cur1 = alloc((size_t)12 * 256 * 16 * 44); // 2,162,688
  float* cur2 = alloc((size_t)12 * 256 * 8 * 22);  //   540,672
  float* bqA = alloc(2560000);
  float* bqB = alloc(2560000);
  float* qtmpR = alloc(2880000);  // qtmp f32 | s_hl | t1_hl | Av part1
  float* slotsR = alloc(2560000); // slots f32 | tb_hl | Av part2 (contiguous with qtmpR)
  float* qpR = alloc(2560000);    // qp_hl ushorts
  float* wcatR = alloc(73728);    // 147456 ushorts
  float* woutR = alloc(65536);
  float* wts1R = alloc(65536);
  float* wts2R = alloc(65536);
  float* wcombR = alloc(196608);  // 393216 ushorts
  float* bcat = alloc(512);
  float* e2 = alloc(4608);
  (void)ws_size; (void)in_sizes; (void)n_in; (void)out_size;

  float* qtmp = qtmpR;
  float* slots = slotsR;
  unsigned short* s_h = (unsigned short*)qtmpR;   unsigned short* s_l = s_h + 2560000;
  unsigned short* t1_h = (unsigned short*)qtmpR;  unsigned short* t1_l = t1_h + 2560000;
  unsigned short* tb_h = (unsigned short*)slotsR; unsigned short* tb_l = tb_h + 2560000;
  unsigned short* qp_h = (unsigned short*)qpR;    unsigned short* qp_l = qp_h + 2560000;
  unsigned short* av_h = (unsigned short*)qtmpR;  unsigned short* av_l = av_h + (size_t)16896 * 256;
  unsigned short* wcat_h = (unsigned short*)wcatR;   unsigned short* wcat_l = wcat_h + 288 * 256;
  unsigned short* wout_h = (unsigned short*)woutR;   unsigned short* wout_l = wout_h + 65536;
  unsigned short* wts1_h = (unsigned short*)wts1R;   unsigned short* wts1_l = wts1_h + 65536;
  unsigned short* wts2_h = (unsigned short*)wts2R;   unsigned short* wts2_l = wts2_h + 65536;
  unsigned short* wcomb_h = (unsigned short*)wcombR; unsigned short* wcomb_l = wcomb_h + 3 * 65536;

  // ---- precompute ----
  pool2x2<<<(2162688 + 255) / 256, 256, 0, stream>>>(imgs, cur1, 16, 44, 2162688);
  pool2x2<<<(540672 + 255) / 256, 256, 0, stream>>>(cur1, cur2, 8, 22, 540672);
  buildcat<<<288, 256, 0, stream>>>(woff, boff, wattn, battn, wcat_h, wcat_l, bcat);
  conv_w<<<256, 256, 0, stream>>>(wout, 256, wout_h, wout_l);
  conv_w<<<256, 256, 0, stream>>>(wts1, 256, wts1_h, wts1_l);
  conv_w<<<256, 256, 0, stream>>>(wts2, 256, wts2_h, wts2_l);
  wcombk<<<768, 256, 0, stream>>>(wfpn, wval, wcomb_h, wcomb_l);
  e2k<<<18, 256, 0, stream>>>(cams, lev, bfpn, wval, bval, e2);

  auto run_value = [&](int b) {
    // level 0
    conv_v<<<dim3(88, 8, 6), 256, 0, stream>>>(imgs + (size_t)b * 4325376, 2816, av_h, av_l);
    gemm_mfma<<<dim3(22, 2, 6), 256, 0, stream>>>(av_h, av_l, wcomb_h, wcomb_l, 2816, 256,
        (long long)2816 * 256, (long long)946176, 768, e2, nullptr, nullptr,
        v, 256, nullptr, nullptr, 0);
    // level 1
    conv_v<<<dim3(22, 8, 6), 256, 0, stream>>>(cur1 + (size_t)b * 1081344, 704, av_h, av_l);
    gemm_mfma<<<dim3(6, 2, 6), 256, 0, stream>>>(av_h, av_l, wcomb_h + 65536, wcomb_l + 65536, 704, 256,
        (long long)704 * 256, (long long)946176, 768, e2 + 256, nullptr, nullptr,
        v + (size_t)2816 * 256, 256, nullptr, nullptr, 0);
    // level 2
    conv_v<<<dim3(6, 8, 6), 256, 0, stream>>>(cur2 + (size_t)b * 270336, 176, av_h, av_l);
    gemm_mfma<<<dim3(2, 2, 6), 256, 0, stream>>>(av_h, av_l, wcomb_h + 131072, wcomb_l + 131072, 176, 256,
        (long long)176 * 256, (long long)946176, 768, e2 + 512, nullptr, nullptr,
        v + (size_t)3520 * 256, 256, nullptr, nullptr, 0);
  };

  auto run_iter = [&](const float* qin_f32, float* qout, int b) {
    // g1: (q+pos) @ [w_off|w_attn] + [b_off|b_attn] -> qtmp (fp32, ldc 288)
    gemm_mfma<<<dim3(79, 3, 1), 256, 0, stream>>>(qp_h, qp_l, wcat_h, wcat_l, 10000, 288,
        0, 0, 0, bcat, nullptr, nullptr, qtmp, 288, nullptr, nullptr, 0);
    // sampling
    sca_sample<<<10000, 256, 0, stream>>>(qtmp, v, l2i + b * 96, slots);
    // split slots
    conv_a<<<2500, 256, 0, stream>>>((const float4*)slots, nullptr, (ushort4*)s_h, (ushort4*)s_l, 640000);
    // g2: slots@wout + bout + resid -> tb (bf16 only)
    gemm_mfma<<<dim3(79, 2, 1), 256, 0, stream>>>(s_h, s_l, wout_h, wout_l, 10000, 256,
        0, 0, 0, bout, qin_f32, nullptr, nullptr, 256, tb_h, tb_l, 0);
    // g3: relu(tb@wts1 + bts1) -> t1 (bf16 only)
    gemm_mfma<<<dim3(79, 2, 1), 256, 0, stream>>>(tb_h, tb_l, wts1_h, wts1_l, 10000, 256,
        0, 0, 0, bts1, nullptr, nullptr, nullptr, 256, t1_h, t1_l, 1);
    // g4: t1@wts2 + bts2 -> qout (fp32) + qp = split(qout + pos)
    gemm_mfma<<<dim3(79, 2, 1), 256, 0, stream>>>(t1_h, t1_l, wts2_h, wts2_l, 10000, 256,
        0, 0, 0, bts2, nullptr, bev_pos, qout, 256, qp_h, qp_l, 0);
  };

  // initial qp = split(bev_query + pos)
  conv_a<<<2500, 256, 0, stream>>>((const float4*)bev_query, (const float4*)bev_pos,
                                   (ushort4*)qp_h, (ushort4*)qp_l, 640000);
  run_value(0);
  run_iter(bev_query, bqA, 0);
  run_iter(bqA, bqB, 0);   // bqB = ego
  run_value(1);
  run_iter(bqB, bqA, 1);   // bqA = nb
  final_copy<<<10000, 256, 0, stream>>>(bqB, bqA, (float*)d_out);
}

// Round 3
// 569.745 us; speedup vs baseline: 1.9076x; 1.7010x over previous
//
#include <hip/hip_runtime.h>
#include <math.h>

typedef __attribute__((ext_vector_type(8))) short bf16x8;
typedef __attribute__((ext_vector_type(4))) float f32x4;

__device__ __forceinline__ unsigned short f2bf(float x) {
  union { float f; unsigned int u; } v; v.f = x;
  unsigned int r = v.u + 0x7fffu + ((v.u >> 16) & 1u);
  return (unsigned short)(r >> 16);
}
__device__ __forceinline__ float bf2f(unsigned short b) {
  union { unsigned int u; float f; } v; v.u = ((unsigned int)b) << 16; return v.f;
}
__device__ __forceinline__ void split2(float x, unsigned short& h, unsigned short& l) {
  h = f2bf(x);
  l = f2bf(x - bf2f(h));
}

// ---------------- pooling (2x2 mean) ----------------
__global__ __launch_bounds__(256) void pool2x2(const float* __restrict__ in, float* __restrict__ out,
                                               int h, int w, int total)
{
  int i = blockIdx.x * 256 + threadIdx.x;
  if (i >= total) return;
  int x = i % w; int r = i / w; int y = r % h; int ci = r / h;
  const float* p = in + (size_t)ci * (4 * h * w) + (size_t)(2 * y) * (2 * w) + 2 * x;
  out[i] = (p[0] + p[1] + p[2 * w] + p[2 * w + 1]) * 0.25f;
}

// ---------------- merged weight prep ----------------
__global__ __launch_bounds__(256) void prep(
    const float* __restrict__ wo, const float* __restrict__ bo,
    const float* __restrict__ wa, const float* __restrict__ ba,
    const float* __restrict__ wout, const float* __restrict__ wts1, const float* __restrict__ wts2,
    const float* __restrict__ wfpn, const float* __restrict__ wval,
    const float* __restrict__ cams, const float* __restrict__ lev,
    const float* __restrict__ bfpn, const float* __restrict__ bval,
    unsigned short* __restrict__ wcatH, unsigned short* __restrict__ wcatL, float* __restrict__ bcat,
    unsigned short* __restrict__ woutH, unsigned short* __restrict__ woutL,
    unsigned short* __restrict__ wts1H, unsigned short* __restrict__ wts1L,
    unsigned short* __restrict__ wts2H, unsigned short* __restrict__ wts2L,
    unsigned short* __restrict__ wcombH, unsigned short* __restrict__ wcombL,
    float* __restrict__ e2)
{
  int bb = blockIdx.x, t = threadIdx.x;
  if (bb < 768) { // wcombT[l][n][k] = (wfpn[l]@wval)^T split
    int l = bb >> 8, i = bb & 255, j = t;
    const float* a = wfpn + ((size_t)l * 256 + i) * 256;
    float acc = 0.f;
    for (int k = 0; k < 256; ++k) acc = fmaf(a[k], wval[(size_t)k * 256 + j], acc);
    unsigned short h, lo; split2(acc, h, lo);
    size_t o = ((size_t)l * 256 + j) * 256 + i;
    wcombH[o] = h; wcombL[o] = lo;
  } else if (bb < 1056) { // wcatT (288,256) split + bcat
    int i = (bb - 768) * 256 + t;
    int c = i >> 8, k = i & 255;
    float v = (c < 192) ? wo[k * 192 + c] : wa[k * 96 + (c - 192)];
    unsigned short h, l; split2(v, h, l);
    wcatH[i] = h; wcatL[i] = l;
    if (i < 288) bcat[i] = (i < 192) ? bo[i] : ba[i - 192];
  } else if (bb < 1824) { // conv_w for wout/wts1/wts2
    int sel = (bb - 1056) >> 8;
    int i = ((bb - 1056) & 255) * 256 + t;
    int nn = i >> 8, k = i & 255;
    const float* B = (sel == 0) ? wout : (sel == 1) ? wts1 : wts2;
    unsigned short* H = (sel == 0) ? woutH : (sel == 1) ? wts1H : wts2H;
    unsigned short* L = (sel == 0) ? woutL : (sel == 1) ? wts1L : wts2L;
    float v = B[(size_t)k * 256 + nn];
    unsigned short h, l; split2(v, h, l);
    H[i] = h; L[i] = l;
  } else { // e2
    int e = bb - 1824;
    int n = e / 3, l = e % 3, j = t;
    float acc = bval[j];
    for (int k = 0; k < 256; ++k) {
      float s = cams[n * 256 + k] + lev[l * 256 + k] + bfpn[l * 256 + k];
      acc = fmaf(s, wval[(size_t)k * 256 + j], acc);
    }
    e2[(size_t)e * 256 + j] = acc;
  }
}

// ---------------- fused value kernel: transpose+split imgs tile, GEMM with wcomb, write V ----------------
__global__ __launch_bounds__(256) void value_fused(
    const float* __restrict__ img0, const float* __restrict__ cur1, const float* __restrict__ cur2,
    const unsigned short* __restrict__ wcH, const unsigned short* __restrict__ wcL,
    const float* __restrict__ e2, float* __restrict__ V)
{
  __shared__ __align__(16) unsigned short AS[2][32][32][8];
  int t = threadIdx.x, wid = t >> 6, lane = t & 63, l15 = lane & 15, lk = lane >> 4;
  int bx = blockIdx.x, cam = blockIdx.y;
  int level, tb, hw; const float* src;
  if (bx < 88)       { level = 0; tb = bx;       hw = 2816; src = img0; }
  else if (bx < 110) { level = 1; tb = bx - 88;  hw = 704;  src = cur1; }
  else               { level = 2; tb = bx - 110; hw = 176;  src = cur2; }
  int p0 = tb * 32;
  const int LST[3] = {0, 2816, 3520};
  src += (size_t)cam * 256 * hw;

  { // stage: (k-major) -> LDS (pos, k) hi/lo
    int f4g = t & 7, kb = t >> 3;
    bool full = (p0 + 32 <= hw);
#pragma unroll
    for (int j = 0; j < 8; ++j) {
      int k = kb + j * 32;
      const float* row = src + (size_t)k * hw;
      int p = p0 + 4 * f4g;
      float4 v;
      if (full) v = *(const float4*)(row + p);
      else {
        v.x = (p < hw) ? row[p] : 0.f;     v.y = (p + 1 < hw) ? row[p + 1] : 0.f;
        v.z = (p + 2 < hw) ? row[p + 2] : 0.f; v.w = (p + 3 < hw) ? row[p + 3] : 0.f;
      }
      int ch = k >> 3, ko = k & 7;
      unsigned short h, l;
      split2(v.x, h, l); AS[0][ch][4 * f4g + 0][ko] = h; AS[1][ch][4 * f4g + 0][ko] = l;
      split2(v.y, h, l); AS[0][ch][4 * f4g + 1][ko] = h; AS[1][ch][4 * f4g + 1][ko] = l;
      split2(v.z, h, l); AS[0][ch][4 * f4g + 2][ko] = h; AS[1][ch][4 * f4g + 2][ko] = l;
      split2(v.w, h, l); AS[0][ch][4 * f4g + 3][ko] = h; AS[1][ch][4 * f4g + 3][ko] = l;
    }
  }
  __syncthreads();

  const unsigned short* AH = wcH + (size_t)level * 65536;
  const unsigned short* AL = wcL + (size_t)level * 65536;
  f32x4 zed = {0.f, 0.f, 0.f, 0.f};
  f32x4 acc[4][2];
#pragma unroll
  for (int mf = 0; mf < 4; ++mf)
#pragma unroll
    for (int nf = 0; nf < 2; ++nf) acc[mf][nf] = zed;
#pragma unroll
  for (int ks = 0; ks < 8; ++ks) {
    bf16x8 bqh[2], bql[2];
#pragma unroll
    for (int nf = 0; nf < 2; ++nf) {
      bqh[nf] = *(const bf16x8*)&AS[0][ks * 4 + lk][nf * 16 + l15][0];
      bql[nf] = *(const bf16x8*)&AS[1][ks * 4 + lk][nf * 16 + l15][0];
    }
#pragma unroll
    for (int mf = 0; mf < 4; ++mf) {
      int m = wid * 64 + mf * 16 + l15;
      size_t bo = (size_t)m * 256 + ks * 32 + lk * 8;
      bf16x8 ah = *(const bf16x8*)(AH + bo);
      bf16x8 al = *(const bf16x8*)(AL + bo);
#pragma unroll
      for (int nf = 0; nf < 2; ++nf) {
        acc[mf][nf] = __builtin_amdgcn_mfma_f32_16x16x32_bf16(ah, bqh[nf], acc[mf][nf], 0, 0, 0);
        acc[mf][nf] = __builtin_amdgcn_mfma_f32_16x16x32_bf16(ah, bql[nf], acc[mf][nf], 0, 0, 0);
        acc[mf][nf] = __builtin_amdgcn_mfma_f32_16x16x32_bf16(al, bqh[nf], acc[mf][nf], 0, 0, 0);
      }
    }
  }
  // epilogue: row=out-channel, col=pos
  const float* bias = e2 + (size_t)(cam * 3 + level) * 256;
  float* Vb = V + ((size_t)cam * 3696 + LST[level] + p0) * 256;
  int lg = lane >> 4;
#pragma unroll
  for (int mf = 0; mf < 4; ++mf) {
    int chb = wid * 64 + mf * 16 + lg * 4;
    float4 b4 = *(const float4*)(bias + chb);
#pragma unroll
    for (int nf = 0; nf < 2; ++nf) {
      int q = nf * 16 + l15;
      if (p0 + q >= hw) continue;
      float4 o;
      o.x = acc[mf][nf][0] + b4.x; o.y = acc[mf][nf][1] + b4.y;
      o.z = acc[mf][nf][2] + b4.z; o.w = acc[mf][nf][3] + b4.w;
      *(float4*)(Vb + (size_t)q * 256 + chb) = o;
    }
  }
}

// ---------------- fused iteration kernel ----------------
// init=1: stage split(qin+pos), compute qtmp only.
// init=0: stage split(slots); g2: @wout+bout+qin; g3: relu(@wts1+bts1); g4: @wts2+bts2 -> qout
//         (+outA/outB copies); then if qtmp: stage split(qout+pos), g1': @wcat+bcat -> qtmp.
__global__ __launch_bounds__(256) void fused_iter(
    const float* __restrict__ slots, const float* __restrict__ qin, const float* __restrict__ pos,
    const unsigned short* __restrict__ woutH, const unsigned short* __restrict__ woutL,
    const unsigned short* __restrict__ wts1H, const unsigned short* __restrict__ wts1L,
    const unsigned short* __restrict__ wts2H, const unsigned short* __restrict__ wts2L,
    const unsigned short* __restrict__ wcatH, const unsigned short* __restrict__ wcatL,
    const float* __restrict__ bout, const float* __restrict__ bts1,
    const float* __restrict__ bts2, const float* __restrict__ bcat,
    float* __restrict__ qout, float* __restrict__ outA, float* __restrict__ outB,
    float* __restrict__ qtmp, int init)
{
  __shared__ __align__(16) unsigned short AS[2][32][32][8];
  int t = threadIdx.x, wid = t >> 6, lane = t & 63, l15 = lane & 15, lk = lane >> 4;
  int lg = lk;
  int r0 = blockIdx.x * 32;
  int rl = t & 31;
  int rg = r0 + rl; int rc = rg > 9999 ? 9999 : rg;

  // ---- phase 0: stage B-side (queries) ----
  {
    int cb8 = (t >> 5) * 4;
    const float* base = (init ? qin : slots) + (size_t)rc * 256;
    const float* pbase = pos + (size_t)rc * 256;
#pragma unroll
    for (int j = 0; j < 4; ++j) {
      int ch = cb8 + j, k0 = ch * 8;
      float4 a0 = *(const float4*)(base + k0);
      float4 a1 = *(const float4*)(base + k0 + 4);
      if (init) {
        float4 p0v = *(const float4*)(pbase + k0);
        float4 p1v = *(const float4*)(pbase + k0 + 4);
        a0.x += p0v.x; a0.y += p0v.y; a0.z += p0v.z; a0.w += p0v.w;
        a1.x += p1v.x; a1.y += p1v.y; a1.z += p1v.z; a1.w += p1v.w;
      }
      bf16x8 hv, lv; unsigned short h, l;
      split2(a0.x, h, l); hv[0] = (short)h; lv[0] = (short)l;
      split2(a0.y, h, l); hv[1] = (short)h; lv[1] = (short)l;
      split2(a0.z, h, l); hv[2] = (short)h; lv[2] = (short)l;
      split2(a0.w, h, l); hv[3] = (short)h; lv[3] = (short)l;
      split2(a1.x, h, l); hv[4] = (short)h; lv[4] = (short)l;
      split2(a1.y, h, l); hv[5] = (short)h; lv[5] = (short)l;
      split2(a1.z, h, l); hv[6] = (short)h; lv[6] = (short)l;
      split2(a1.w, h, l); hv[7] = (short)h; lv[7] = (short)l;
      *(bf16x8*)&AS[0][ch][rl][0] = hv;
      *(bf16x8*)&AS[1][ch][rl][0] = lv;
    }
  }
  __syncthreads();

  f32x4 zed = {0.f, 0.f, 0.f, 0.f};
  f32x4 acc[4][2];

  auto gemmT = [&](const unsigned short* AH, const unsigned short* AL) {
#pragma unroll
    for (int mf = 0; mf < 4; ++mf)
#pragma unroll
      for (int nf = 0; nf < 2; ++nf) acc[mf][nf] = zed;
#pragma unroll
    for (int ks = 0; ks < 8; ++ks) {
      bf16x8 bqh[2], bql[2];
#pragma unroll
      for (int nf = 0; nf < 2; ++nf) {
        bqh[nf] = *(const bf16x8*)&AS[0][ks * 4 + lk][nf * 16 + l15][0];
        bql[nf] = *(const bf16x8*)&AS[1][ks * 4 + lk][nf * 16 + l15][0];
      }
#pragma unroll
      for (int mf = 0; mf < 4; ++mf) {
        int m = wid * 64 + mf * 16 + l15;
        size_t bo = (size_t)m * 256 + ks * 32 + lk * 8;
        bf16x8 ah = *(const bf16x8*)(AH + bo);
        bf16x8 al = *(const bf16x8*)(AL + bo);
#pragma unroll
        for (int nf = 0; nf < 2; ++nf) {
          acc[mf][nf] = __builtin_amdgcn_mfma_f32_16x16x32_bf16(ah, bqh[nf], acc[mf][nf], 0, 0, 0);
          acc[mf][nf] = __builtin_amdgcn_mfma_f32_16x16x32_bf16(ah, bql[nf], acc[mf][nf], 0, 0, 0);
          acc[mf][nf] = __builtin_amdgcn_mfma_f32_16x16x32_bf16(al, bqh[nf], acc[mf][nf], 0, 0, 0);
        }
      }
    }
  };

  if (!init) {
    // ---- g2: slots@wout + bout + qin ----
    gemmT(woutH, woutL);
    __syncthreads();
#pragma unroll
    for (int mf = 0; mf < 4; ++mf) {
      int chb = wid * 64 + mf * 16 + lg * 4;
      float4 b4 = *(const float4*)(bout + chb);
#pragma unroll
      for (int nf = 0; nf < 2; ++nf) {
        int q = nf * 16 + l15;
        int qg = r0 + q; int qc = qg > 9999 ? 9999 : qg;
        float4 rr = *(const float4*)(qin + (size_t)qc * 256 + chb);
        float v0 = acc[mf][nf][0] + b4.x + rr.x;
        float v1 = acc[mf][nf][1] + b4.y + rr.y;
        float v2 = acc[mf][nf][2] + b4.z + rr.z;
        float v3 = acc[mf][nf][3] + b4.w + rr.w;
        ushort4 hh, ll;
        split2(v0, hh.x, ll.x); split2(v1, hh.y, ll.y);
        split2(v2, hh.z, ll.z); split2(v3, hh.w, ll.w);
        *(ushort4*)&AS[0][chb >> 3][q][chb & 7] = hh;
        *(ushort4*)&AS[1][chb >> 3][q][chb & 7] = ll;
      }
    }
    __syncthreads();
    // ---- g3: relu(@wts1 + bts1) ----
    gemmT(wts1H, wts1L);
    __syncthreads();
#pragma unroll
    for (int mf = 0; mf < 4; ++mf) {
      int chb = wid * 64 + mf * 16 + lg * 4;
      float4 b4 = *(const float4*)(bts1 + chb);
#pragma unroll
      for (int nf = 0; nf < 2; ++nf) {
        int q = nf * 16 + l15;
        float v0 = fmaxf(acc[mf][nf][0] + b4.x, 0.f);
        float v1 = fmaxf(acc[mf][nf][1] + b4.y, 0.f);
        float v2 = fmaxf(acc[mf][nf][2] + b4.z, 0.f);
        float v3 = fmaxf(acc[mf][nf][3] + b4.w, 0.f);
        ushort4 hh, ll;
        split2(v0, hh.x, ll.x); split2(v1, hh.y, ll.y);
        split2(v2, hh.z, ll.z); split2(v3, hh.w, ll.w);
        *(ushort4*)&AS[0][chb >> 3][q][chb & 7] = hh;
        *(ushort4*)&AS[1][chb >> 3][q][chb & 7] = ll;
      }
    }
    __syncthreads();
    // ---- g4: @wts2 + bts2 -> qout (+copies); stage qp=qout+pos if qtmp ----
    gemmT(wts2H, wts2L);
    __syncthreads();
#pragma unroll
    for (int mf = 0; mf < 4; ++mf) {
      int chb = wid * 64 + mf * 16 + lg * 4;
      float4 b4 = *(const float4*)(bts2 + chb);
#pragma unroll
      for (int nf = 0; nf < 2; ++nf) {
        int q = nf * 16 + l15;
        int qg = r0 + q;
        float4 o;
        o.x = acc[mf][nf][0] + b4.x; o.y = acc[mf][nf][1] + b4.y;
        o.z = acc[mf][nf][2] + b4.z; o.w = acc[mf][nf][3] + b4.w;
        if (qg < 10000) {
          size_t go = (size_t)qg * 256 + chb;
          *(float4*)(qout + go) = o;
          if (outA) { *(float4*)(outA + go) = o; *(float4*)(outB + go) = o; }
        }
        if (qtmp) {
          int qc = qg > 9999 ? 9999 : qg;
          float4 pv = *(const float4*)(pos + (size_t)qc * 256 + chb);
          ushort4 hh, ll;
          split2(o.x + pv.x, hh.x, ll.x); split2(o.y + pv.y, hh.y, ll.y);
          split2(o.z + pv.z, hh.z, ll.z); split2(o.w + pv.w, hh.w, ll.w);
          *(ushort4*)&AS[0][chb >> 3][q][chb & 7] = hh;
          *(ushort4*)&AS[1][chb >> 3][q][chb & 7] = ll;
        }
      }
    }
    if (!qtmp) return;
    __syncthreads();
  }

  // ---- g1': qp @ wcat + bcat -> qtmp (288 cols) ----
  {
    const int CB[4] = {0, 80, 160, 224};
    int cb = CB[wid];
    int mfw = (wid < 2) ? 5 : 4;
    f32x4 acc2[5][2];
#pragma unroll
    for (int mf = 0; mf < 5; ++mf)
#pragma unroll
      for (int nf = 0; nf < 2; ++nf) acc2[mf][nf] = zed;
#pragma unroll
    for (int ks = 0; ks < 8; ++ks) {
      bf16x8 bqh[2], bql[2];
#pragma unroll
      for (int nf = 0; nf < 2; ++nf) {
        bqh[nf] = *(const bf16x8*)&AS[0][ks * 4 + lk][nf * 16 + l15][0];
        bql[nf] = *(const bf16x8*)&AS[1][ks * 4 + lk][nf * 16 + l15][0];
      }
#pragma unroll
      for (int mf = 0; mf < 5; ++mf) {
        if (mf >= mfw) continue;
        int m = cb + mf * 16 + l15;
        size_t bo = (size_t)m * 256 + ks * 32 + lk * 8;
        bf16x8 ah = *(const bf16x8*)(wcatH + bo);
        bf16x8 al = *(const bf16x8*)(wcatL + bo);
#pragma unroll
        for (int nf = 0; nf < 2; ++nf) {
          acc2[mf][nf] = __builtin_amdgcn_mfma_f32_16x16x32_bf16(ah, bqh[nf], acc2[mf][nf], 0, 0, 0);
          acc2[mf][nf] = __builtin_amdgcn_mfma_f32_16x16x32_bf16(ah, bql[nf], acc2[mf][nf], 0, 0, 0);
          acc2[mf][nf] = __builtin_amdgcn_mfma_f32_16x16x32_bf16(al, bqh[nf], acc2[mf][nf], 0, 0, 0);
        }
      }
    }
#pragma unroll
    for (int mf = 0; mf < 5; ++mf) {
      if (mf >= mfw) continue;
      int chb = cb + mf * 16 + lg * 4;
      float4 b4 = *(const float4*)(bcat + chb);
#pragma unroll
      for (int nf = 0; nf < 2; ++nf) {
        int q = nf * 16 + l15;
        int qg = r0 + q;
        if (qg >= 10000) continue;
        float4 o;
        o.x = acc2[mf][nf][0] + b4.x; o.y = acc2[mf][nf][1] + b4.y;
        o.z = acc2[mf][nf][2] + b4.z; o.w = acc2[mf][nf][3] + b4.w;
        *(float4*)(qtmp + (size_t)qg * 288 + chb) = o;
      }
    }
  }
}

// ---------------- deformable sampling + attention + cam-average -> slots ----------------
__global__ __launch_bounds__(256) void sca_sample(const float* __restrict__ qtmp, const float* __restrict__ V,
                                                  const float* __restrict__ l2i, float* __restrict__ slots)
{
  int q = blockIdx.x;
  int t = threadIdx.x;
  int head = t >> 5;
  __shared__ float raw[288];
  __shared__ float attnS[96];
  __shared__ float refx[6][4], refy[6][4];
  __shared__ int mnd[24];
  __shared__ int validn[6];
  __shared__ __align__(16) float w4[576][4];
  __shared__ __align__(16) int o4[576][4];

  raw[t] = qtmp[(size_t)q * 288 + t];
  if (t < 32) raw[256 + t] = qtmp[(size_t)q * 288 + 256 + t];
  if (t >= 32 && t < 56) {
    int tt = t - 32;
    int n = tt >> 2, d = tt & 3;
    const float* Mrow = l2i + n * 16;
    int qx = q % 100, qy = q / 100;
    float X = ((qx + 0.5f) / 100.0f) * 102.4f + (-51.2f);
    float Y = ((qy + 0.5f) / 100.0f) * 102.4f + (-51.2f);
    float zi = (d == 3) ? 7.5f : (0.5f + (float)d * (7.0f / 3.0f));
    float Z = zi + (-5.0f);
    float px = Mrow[0] * X + Mrow[1] * Y + Mrow[2] * Z + Mrow[3];
    float py = Mrow[4] * X + Mrow[5] * Y + Mrow[6] * Z + Mrow[7];
    float pz = Mrow[8] * X + Mrow[9] * Y + Mrow[10] * Z + Mrow[11];
    float dz = fmaxf(pz, 1e-5f);
    float xc = (px / dz) / 704.0f;
    float yc = (py / dz) / 256.0f;
    refx[n][d] = xc; refy[n][d] = yc;
    mnd[n * 4 + d] = (pz > 1e-5f) && (xc > 0.f) && (xc < 1.f) && (yc > 0.f) && (yc < 1.f);
  }
  __syncthreads();
  if (t < 8) {
    float mx = raw[192 + t * 12];
    for (int p = 1; p < 12; ++p) mx = fmaxf(mx, raw[192 + t * 12 + p]);
    float s = 0.f;
    float e[12];
#pragma unroll
    for (int p = 0; p < 12; ++p) { e[p] = __expf(raw[192 + t * 12 + p] - mx); s += e[p]; }
    float inv = 1.f / s;
#pragma unroll
    for (int p = 0; p < 12; ++p) attnS[t * 12 + p] = e[p] * inv;
  } else if (t < 14) {
    int n = t - 8;
    validn[n] = mnd[n * 4] | mnd[n * 4 + 1] | mnd[n * 4 + 2] | mnd[n * 4 + 3];
  }
  __syncthreads();

  // local compact list of valid cams (packed 3-bit)
  int packed = 0, nv = 0;
  for (int n = 0; n < 6; ++n) {
    if (validn[n]) { packed |= n << (3 * nv); nv++; }
  }

  const float WWf[3] = {88.f, 44.f, 22.f}, HHf[3] = {32.f, 16.f, 8.f};
  const int WWi[3] = {88, 44, 22}, STi[3] = {0, 2816, 3520};
  int npts = nv * 96;
  for (int pt = t; pt < npts; pt += 256) {
    int hd = pt & 7;
    int g = pt >> 3;
    int j = g % 12, ni = g / 12;
    int n = (packed >> (3 * ni)) & 7;
    int l = j >> 2, d = j & 3;
    float wwf = WWf[l], hhf = HHf[l];
    int wwi = WWi[l], st = STi[l];
    float a = attnS[hd * 12 + j];
    float ox = raw[hd * 24 + l * 8 + d * 2 + 0];
    float oy = raw[hd * 24 + l * 8 + d * 2 + 1];
    float x = refx[n][d] * wwf + ox - 0.5f;
    float y = refy[n][d] * hhf + oy - 0.5f;
    float x0 = floorf(x), y0 = floorf(y);
    float fx = x - x0, fy = y - y0;
    float wx0 = 1.f - fx, wy0 = 1.f - fy;
    float vx0 = (x0 >= 0.f && x0 < wwf) ? 1.f : 0.f;
    float vx1 = (x0 + 1.f >= 0.f && x0 + 1.f < wwf) ? 1.f : 0.f;
    float vy0 = (y0 >= 0.f && y0 < hhf) ? 1.f : 0.f;
    float vy1 = (y0 + 1.f >= 0.f && y0 + 1.f < hhf) ? 1.f : 0.f;
    w4[pt][0] = a * wx0 * wy0 * vx0 * vy0;
    w4[pt][1] = a * fx * wy0 * vx1 * vy0;
    w4[pt][2] = a * wx0 * fy * vx0 * vy1;
    w4[pt][3] = a * fx * fy * vx1 * vy1;
    int ix0 = (int)fminf(fmaxf(x0, 0.f), wwf - 1.f);
    int ix1 = (int)fminf(fmaxf(x0 + 1.f, 0.f), wwf - 1.f);
    int iy0 = (int)fminf(fmaxf(y0, 0.f), hhf - 1.f);
    int iy1 = (int)fminf(fmaxf(y0 + 1.f, 0.f), hhf - 1.f);
    int rA = (st + iy0 * wwi) * 256, rB = (st + iy1 * wwi) * 256;
    o4[pt][0] = rA + ix0 * 256;
    o4[pt][1] = rA + ix1 * 256;
    o4[pt][2] = rB + ix0 * 256;
    o4[pt][3] = rB + ix1 * 256;
  }
  __syncthreads();

  float invc = 1.f / (float)(nv > 1 ? nv : 1);
  float accv = 0.f;
  for (int ni = 0; ni < nv; ++ni) {
    int n = (packed >> (3 * ni)) & 7;
    const float* Vn = V + (size_t)n * 946176 + t;
    int pb = ni * 96 + head;
#pragma unroll
    for (int j = 0; j < 12; ++j) {
      int pt = pb + j * 8;
      float4 w = *reinterpret_cast<const float4*>(&w4[pt][0]);
      int4 o = *reinterpret_cast<const int4*>(&o4[pt][0]);
      accv = fmaf(w.x, Vn[o.x], accv);
      accv = fmaf(w.y, Vn[o.y], accv);
      accv = fmaf(w.z, Vn[o.z], accv);
      accv = fmaf(w.w, Vn[o.w], accv);
    }
  }
  slots[(size_t)q * 256 + t] = accv * invc;
}

extern "C" void kernel_launch(void* const* d_in, const int* in_sizes, int n_in,
                              void* d_out, int out_size, void* d_ws, size_t ws_size,
                              hipStream_t stream)
{
  const float* imgs = (const float*)d_in[0];
  const float* l2i = (const float*)d_in[1];
  const float* bev_query = (const float*)d_in[2];
  const float* bev_pos = (const float*)d_in[3];
  const float* cams = (const float*)d_in[4];
  const float* lev = (const float*)d_in[5];
  const float* wfpn = (const float*)d_in[6];
  const float* bfpn = (const float*)d_in[7];
  const float* wval = (const float*)d_in[8];
  const float* bval = (const float*)d_in[9];
  const float* woff = (const float*)d_in[10];
  const float* boff = (const float*)d_in[11];
  const float* wattn = (const float*)d_in[12];
  const float* battn = (const float*)d_in[13];
  const float* wout = (const float*)d_in[14];
  const float* bout = (const float*)d_in[15];
  const float* wts1 = (const float*)d_in[16];
  const float* bts1 = (const float*)d_in[17];
  const float* wts2 = (const float*)d_in[18];
  const float* bts2 = (const float*)d_in[19];

  float* W = (float*)d_ws;
  size_t off = 0;
  auto alloc = [&](size_t n) { float* p = W + off; off += n; return p; };
  float* v    = alloc((size_t)6 * 3696 * 256);     // 5,677,056
  float* cur1 = alloc((size_t)12 * 256 * 16 * 44); // 2,162,688
  float* cur2 = alloc((size_t)12 * 256 * 8 * 22);  //   540,672
  float* bqA  = alloc(2560000);
  float* bqB  = alloc(2560000);
  float* qtmp = alloc(2880000);
  float* slots = alloc(2560000);
  float* wcatR = alloc(73728);
  float* woutR = alloc(65536);
  float* wts1R = alloc(65536);
  float* wts2R = alloc(65536);
  float* wcombR = alloc(196608);
  float* bcat = alloc(512);
  float* e2 = alloc(4608);
  (void)ws_size; (void)in_sizes; (void)n_in; (void)out_size;

  unsigned short* wcat_h = (unsigned short*)wcatR;   unsigned short* wcat_l = wcat_h + 288 * 256;
  unsigned short* wout_h = (unsigned short*)woutR;   unsigned short* wout_l = wout_h + 65536;
  unsigned short* wts1_h = (unsigned short*)wts1R;   unsigned short* wts1_l = wts1_h + 65536;
  unsigned short* wts2_h = (unsigned short*)wts2R;   unsigned short* wts2_l = wts2_h + 65536;
  unsigned short* wcomb_h = (unsigned short*)wcombR; unsigned short* wcomb_l = wcomb_h + 3 * 65536;

  float* OUT = (float*)d_out;

  // precompute
  pool2x2<<<8448, 256, 0, stream>>>(imgs, cur1, 16, 44, 2162688);
  pool2x2<<<2112, 256, 0, stream>>>(cur1, cur2, 8, 22, 540672);
  prep<<<1842, 256, 0, stream>>>(woff, boff, wattn, battn, wout, wts1, wts2, wfpn, wval,
                                 cams, lev, bfpn, bval,
                                 wcat_h, wcat_l, bcat, wout_h, wout_l, wts1_h, wts1_l,
                                 wts2_h, wts2_l, wcomb_h, wcomb_l, e2);

  // initial qtmp = (bev_query+pos)@wcat + bcat
  fused_iter<<<313, 256, 0, stream>>>(nullptr, bev_query, bev_pos,
      wout_h, wout_l, wts1_h, wts1_l, wts2_h, wts2_l, wcat_h, wcat_l,
      bout, bts1, bts2, bcat, bqA, nullptr, nullptr, qtmp, 1);

  // value b0
  value_fused<<<dim3(116, 6), 256, 0, stream>>>(imgs, cur1, cur2, wcomb_h, wcomb_l, e2, v);

  // iter 1
  sca_sample<<<10000, 256, 0, stream>>>(qtmp, v, l2i, slots);
  fused_iter<<<313, 256, 0, stream>>>(slots, bev_query, bev_pos,
      wout_h, wout_l, wts1_h, wts1_l, wts2_h, wts2_l, wcat_h, wcat_l,
      bout, bts1, bts2, bcat, bqA, nullptr, nullptr, qtmp, 0);
  // iter 2 -> ego (bqB + d_out groups 0,1)
  sca_sample<<<10000, 256, 0, stream>>>(qtmp, v, l2i, slots);
  fused_iter<<<313, 256, 0, stream>>>(slots, bqA, bev_pos,
      wout_h, wout_l, wts1_h, wts1_l, wts2_h, wts2_l, wcat_h, wcat_l,
      bout, bts1, bts2, bcat, bqB, OUT, OUT + 2560000, qtmp, 0);

  // value b1
  value_fused<<<dim3(116, 6), 256, 0, stream>>>(imgs + (size_t)4325376, cur1 + (size_t)1081344,
                                                cur2 + (size_t)270336, wcomb_h, wcomb_l, e2, v);
  // iter 3 -> nb (directly into d_out)
  sca_sample<<<10000, 256, 0, stream>>>(qtmp, v, l2i + 96, slots);
  fused_iter<<<313, 256, 0, stream>>>(slots, bqB, bev_pos,
      wout_h, wout_l, wts1_h, wts1_l, wts2_h, wts2_l, wcat_h, wcat_l,
      bout, bts1, bts2, bcat, OUT + 5120000, nullptr, nullptr, nullptr, 0);
}

// Round 4
// 552.583 us; speedup vs baseline: 1.9668x; 1.0311x over previous
//
#include <hip/hip_runtime.h>
#include <math.h>

typedef __attribute__((ext_vector_type(8))) short bf16x8;
typedef __attribute__((ext_vector_type(4))) float f32x4;

__device__ __forceinline__ unsigned short f2bf(float x) {
  union { float f; unsigned int u; } v; v.f = x;
  unsigned int r = v.u + 0x7fffu + ((v.u >> 16) & 1u);
  return (unsigned short)(r >> 16);
}
__device__ __forceinline__ float bf2f(unsigned short b) {
  union { unsigned int u; float f; } v; v.u = ((unsigned int)b) << 16; return v.f;
}
__device__ __forceinline__ void split2(float x, unsigned short& h, unsigned short& l) {
  h = f2bf(x);
  l = f2bf(x - bf2f(h));
}

// ---------------- pooling (2x2 mean) ----------------
__global__ __launch_bounds__(256) void pool2x2(const float* __restrict__ in, float* __restrict__ out,
                                               int h, int w, int total)
{
  int i = blockIdx.x * 256 + threadIdx.x;
  if (i >= total) return;
  int x = i % w; int r = i / w; int y = r % h; int ci = r / h;
  const float* p = in + (size_t)ci * (4 * h * w) + (size_t)(2 * y) * (2 * w) + 2 * x;
  out[i] = (p[0] + p[1] + p[2 * w] + p[2 * w + 1]) * 0.25f;
}

// ---------------- merged weight prep ----------------
__global__ __launch_bounds__(256) void prep(
    const float* __restrict__ wo, const float* __restrict__ bo,
    const float* __restrict__ wa, const float* __restrict__ ba,
    const float* __restrict__ wout, const float* __restrict__ wts1, const float* __restrict__ wts2,
    const float* __restrict__ wfpn, const float* __restrict__ wval,
    const float* __restrict__ cams, const float* __restrict__ lev,
    const float* __restrict__ bfpn, const float* __restrict__ bval,
    unsigned short* __restrict__ wcatH, unsigned short* __restrict__ wcatL, float* __restrict__ bcat,
    unsigned short* __restrict__ woutH, unsigned short* __restrict__ woutL,
    unsigned short* __restrict__ wts1H, unsigned short* __restrict__ wts1L,
    unsigned short* __restrict__ wts2H, unsigned short* __restrict__ wts2L,
    unsigned short* __restrict__ wcombH, unsigned short* __restrict__ wcombL,
    float* __restrict__ e2)
{
  int bb = blockIdx.x, t = threadIdx.x;
  if (bb < 768) { // wcombT[l][n][k] = (wfpn[l]@wval)^T split
    int l = bb >> 8, i = bb & 255, j = t;
    const float* a = wfpn + ((size_t)l * 256 + i) * 256;
    float acc = 0.f;
    for (int k = 0; k < 256; ++k) acc = fmaf(a[k], wval[(size_t)k * 256 + j], acc);
    unsigned short h, lo; split2(acc, h, lo);
    size_t o = ((size_t)l * 256 + j) * 256 + i;
    wcombH[o] = h; wcombL[o] = lo;
  } else if (bb < 1056) { // wcatT (288,256) split + bcat
    int i = (bb - 768) * 256 + t;
    int c = i >> 8, k = i & 255;
    float v = (c < 192) ? wo[k * 192 + c] : wa[k * 96 + (c - 192)];
    unsigned short h, l; split2(v, h, l);
    wcatH[i] = h; wcatL[i] = l;
    if (i < 288) bcat[i] = (i < 192) ? bo[i] : ba[i - 192];
  } else if (bb < 1824) { // conv_w for wout/wts1/wts2
    int sel = (bb - 1056) >> 8;
    int i = ((bb - 1056) & 255) * 256 + t;
    int nn = i >> 8, k = i & 255;
    const float* B = (sel == 0) ? wout : (sel == 1) ? wts1 : wts2;
    unsigned short* H = (sel == 0) ? woutH : (sel == 1) ? wts1H : wts2H;
    unsigned short* L = (sel == 0) ? woutL : (sel == 1) ? wts1L : wts2L;
    float v = B[(size_t)k * 256 + nn];
    unsigned short h, l; split2(v, h, l);
    H[i] = h; L[i] = l;
  } else { // e2
    int e = bb - 1824;
    int n = e / 3, l = e % 3, j = t;
    float acc = bval[j];
    for (int k = 0; k < 256; ++k) {
      float s = cams[n * 256 + k] + lev[l * 256 + k] + bfpn[l * 256 + k];
      acc = fmaf(s, wval[(size_t)k * 256 + j], acc);
    }
    e2[(size_t)e * 256 + j] = acc;
  }
}

// ---------------- fused value kernel: transpose+split imgs tile, GEMM with wcomb, write V ----------------
__global__ __launch_bounds__(512) void value_fused(
    const float* __restrict__ img0, const float* __restrict__ cur1, const float* __restrict__ cur2,
    const unsigned short* __restrict__ wcH, const unsigned short* __restrict__ wcL,
    const float* __restrict__ e2, float* __restrict__ V)
{
  __shared__ __align__(16) unsigned short AS[2][32][32][8];
  int t = threadIdx.x, wid = t >> 6, lane = t & 63, l15 = lane & 15, lk = lane >> 4;
  int bx = blockIdx.x, cam = blockIdx.y;
  int level, tb, hw; const float* src;
  if (bx < 88)       { level = 0; tb = bx;       hw = 2816; src = img0; }
  else if (bx < 110) { level = 1; tb = bx - 88;  hw = 704;  src = cur1; }
  else               { level = 2; tb = bx - 110; hw = 176;  src = cur2; }
  int p0 = tb * 32;
  const int LST[3] = {0, 2816, 3520};
  src += (size_t)cam * 256 * hw;

  { // stage: (k-major) -> LDS (pos, k) hi/lo
    int f4g = t & 7, kb = t >> 3;  // kb 0..63
    bool full = (p0 + 32 <= hw);
#pragma unroll
    for (int j = 0; j < 4; ++j) {
      int k = kb + j * 64;
      const float* row = src + (size_t)k * hw;
      int p = p0 + 4 * f4g;
      float4 v;
      if (full) v = *(const float4*)(row + p);
      else {
        v.x = (p < hw) ? row[p] : 0.f;     v.y = (p + 1 < hw) ? row[p + 1] : 0.f;
        v.z = (p + 2 < hw) ? row[p + 2] : 0.f; v.w = (p + 3 < hw) ? row[p + 3] : 0.f;
      }
      int ch = k >> 3, ko = k & 7;
      unsigned short h, l;
      split2(v.x, h, l); AS[0][ch][4 * f4g + 0][ko] = h; AS[1][ch][4 * f4g + 0][ko] = l;
      split2(v.y, h, l); AS[0][ch][4 * f4g + 1][ko] = h; AS[1][ch][4 * f4g + 1][ko] = l;
      split2(v.z, h, l); AS[0][ch][4 * f4g + 2][ko] = h; AS[1][ch][4 * f4g + 2][ko] = l;
      split2(v.w, h, l); AS[0][ch][4 * f4g + 3][ko] = h; AS[1][ch][4 * f4g + 3][ko] = l;
    }
  }
  __syncthreads();

  const unsigned short* AH = wcH + (size_t)level * 65536;
  const unsigned short* AL = wcL + (size_t)level * 65536;
  f32x4 zed = {0.f, 0.f, 0.f, 0.f};
  f32x4 acc[2][2];
#pragma unroll
  for (int mf = 0; mf < 2; ++mf)
#pragma unroll
    for (int nf = 0; nf < 2; ++nf) acc[mf][nf] = zed;
#pragma unroll
  for (int ks = 0; ks < 8; ++ks) {
    bf16x8 bqh[2], bql[2];
#pragma unroll
    for (int nf = 0; nf < 2; ++nf) {
      bqh[nf] = *(const bf16x8*)&AS[0][ks * 4 + lk][nf * 16 + l15][0];
      bql[nf] = *(const bf16x8*)&AS[1][ks * 4 + lk][nf * 16 + l15][0];
    }
#pragma unroll
    for (int mf = 0; mf < 2; ++mf) {
      int m = wid * 32 + mf * 16 + l15;
      size_t bo = (size_t)m * 256 + ks * 32 + lk * 8;
      bf16x8 ah = *(const bf16x8*)(AH + bo);
      bf16x8 al = *(const bf16x8*)(AL + bo);
#pragma unroll
      for (int nf = 0; nf < 2; ++nf) {
        acc[mf][nf] = __builtin_amdgcn_mfma_f32_16x16x32_bf16(ah, bqh[nf], acc[mf][nf], 0, 0, 0);
        acc[mf][nf] = __builtin_amdgcn_mfma_f32_16x16x32_bf16(ah, bql[nf], acc[mf][nf], 0, 0, 0);
        acc[mf][nf] = __builtin_amdgcn_mfma_f32_16x16x32_bf16(al, bqh[nf], acc[mf][nf], 0, 0, 0);
      }
    }
  }
  // epilogue: row=out-channel, col=pos
  const float* bias = e2 + (size_t)(cam * 3 + level) * 256;
  float* Vb = V + ((size_t)cam * 3696 + LST[level] + p0) * 256;
  int lg = lane >> 4;
#pragma unroll
  for (int mf = 0; mf < 2; ++mf) {
    int chb = wid * 32 + mf * 16 + lg * 4;
    float4 b4 = *(const float4*)(bias + chb);
#pragma unroll
    for (int nf = 0; nf < 2; ++nf) {
      int q = nf * 16 + l15;
      if (p0 + q >= hw) continue;
      float4 o;
      o.x = acc[mf][nf][0] + b4.x; o.y = acc[mf][nf][1] + b4.y;
      o.z = acc[mf][nf][2] + b4.z; o.w = acc[mf][nf][3] + b4.w;
      *(float4*)(Vb + (size_t)q * 256 + chb) = o;
    }
  }
}

// ---------------- fused iteration kernel (512 threads, 8 waves) ----------------
__global__ __launch_bounds__(512) void fused_iter(
    const float* __restrict__ slots, const float* __restrict__ qin, const float* __restrict__ pos,
    const unsigned short* __restrict__ woutH, const unsigned short* __restrict__ woutL,
    const unsigned short* __restrict__ wts1H, const unsigned short* __restrict__ wts1L,
    const unsigned short* __restrict__ wts2H, const unsigned short* __restrict__ wts2L,
    const unsigned short* __restrict__ wcatH, const unsigned short* __restrict__ wcatL,
    const float* __restrict__ bout, const float* __restrict__ bts1,
    const float* __restrict__ bts2, const float* __restrict__ bcat,
    float* __restrict__ qout, float* __restrict__ outA, float* __restrict__ outB,
    float* __restrict__ qtmp, int init)
{
  __shared__ __align__(16) unsigned short AS[2][32][32][8];
  int t = threadIdx.x, wid = t >> 6, lane = t & 63, l15 = lane & 15, lk = lane >> 4;
  int lg = lk;
  int r0 = blockIdx.x * 32;
  int rl = t & 31;
  int rg = r0 + rl; int rc = rg > 9999 ? 9999 : rg;

  // ---- phase 0: stage B-side (queries) ----
  {
    int cb2 = (t >> 5) * 2;
    const float* base = (init ? qin : slots) + (size_t)rc * 256;
    const float* pbase = pos + (size_t)rc * 256;
#pragma unroll
    for (int j = 0; j < 2; ++j) {
      int ch = cb2 + j, k0 = ch * 8;
      float4 a0 = *(const float4*)(base + k0);
      float4 a1 = *(const float4*)(base + k0 + 4);
      if (init) {
        float4 p0v = *(const float4*)(pbase + k0);
        float4 p1v = *(const float4*)(pbase + k0 + 4);
        a0.x += p0v.x; a0.y += p0v.y; a0.z += p0v.z; a0.w += p0v.w;
        a1.x += p1v.x; a1.y += p1v.y; a1.z += p1v.z; a1.w += p1v.w;
      }
      bf16x8 hv, lv; unsigned short h, l;
      split2(a0.x, h, l); hv[0] = (short)h; lv[0] = (short)l;
      split2(a0.y, h, l); hv[1] = (short)h; lv[1] = (short)l;
      split2(a0.z, h, l); hv[2] = (short)h; lv[2] = (short)l;
      split2(a0.w, h, l); hv[3] = (short)h; lv[3] = (short)l;
      split2(a1.x, h, l); hv[4] = (short)h; lv[4] = (short)l;
      split2(a1.y, h, l); hv[5] = (short)h; lv[5] = (short)l;
      split2(a1.z, h, l); hv[6] = (short)h; lv[6] = (short)l;
      split2(a1.w, h, l); hv[7] = (short)h; lv[7] = (short)l;
      *(bf16x8*)&AS[0][ch][rl][0] = hv;
      *(bf16x8*)&AS[1][ch][rl][0] = lv;
    }
  }
  __syncthreads();

  f32x4 zed = {0.f, 0.f, 0.f, 0.f};
  f32x4 acc[2][2];

  auto gemmT = [&](const unsigned short* AH, const unsigned short* AL) {
#pragma unroll
    for (int mf = 0; mf < 2; ++mf)
#pragma unroll
      for (int nf = 0; nf < 2; ++nf) acc[mf][nf] = zed;
#pragma unroll
    for (int ks = 0; ks < 8; ++ks) {
      bf16x8 bqh[2], bql[2];
#pragma unroll
      for (int nf = 0; nf < 2; ++nf) {
        bqh[nf] = *(const bf16x8*)&AS[0][ks * 4 + lk][nf * 16 + l15][0];
        bql[nf] = *(const bf16x8*)&AS[1][ks * 4 + lk][nf * 16 + l15][0];
      }
#pragma unroll
      for (int mf = 0; mf < 2; ++mf) {
        int m = wid * 32 + mf * 16 + l15;
        size_t bo = (size_t)m * 256 + ks * 32 + lk * 8;
        bf16x8 ah = *(const bf16x8*)(AH + bo);
        bf16x8 al = *(const bf16x8*)(AL + bo);
#pragma unroll
        for (int nf = 0; nf < 2; ++nf) {
          acc[mf][nf] = __builtin_amdgcn_mfma_f32_16x16x32_bf16(ah, bqh[nf], acc[mf][nf], 0, 0, 0);
          acc[mf][nf] = __builtin_amdgcn_mfma_f32_16x16x32_bf16(ah, bql[nf], acc[mf][nf], 0, 0, 0);
          acc[mf][nf] = __builtin_amdgcn_mfma_f32_16x16x32_bf16(al, bqh[nf], acc[mf][nf], 0, 0, 0);
        }
      }
    }
  };

  if (!init) {
    // ---- g2: slots@wout + bout + qin ----
    gemmT(woutH, woutL);
    __syncthreads();
#pragma unroll
    for (int mf = 0; mf < 2; ++mf) {
      int chb = wid * 32 + mf * 16 + lg * 4;
      float4 b4 = *(const float4*)(bout + chb);
#pragma unroll
      for (int nf = 0; nf < 2; ++nf) {
        int q = nf * 16 + l15;
        int qg = r0 + q; int qc = qg > 9999 ? 9999 : qg;
        float4 rr = *(const float4*)(qin + (size_t)qc * 256 + chb);
        float v0 = acc[mf][nf][0] + b4.x + rr.x;
        float v1 = acc[mf][nf][1] + b4.y + rr.y;
        float v2 = acc[mf][nf][2] + b4.z + rr.z;
        float v3 = acc[mf][nf][3] + b4.w + rr.w;
        ushort4 hh, ll;
        split2(v0, hh.x, ll.x); split2(v1, hh.y, ll.y);
        split2(v2, hh.z, ll.z); split2(v3, hh.w, ll.w);
        *(ushort4*)&AS[0][chb >> 3][q][chb & 7] = hh;
        *(ushort4*)&AS[1][chb >> 3][q][chb & 7] = ll;
      }
    }
    __syncthreads();
    // ---- g3: relu(@wts1 + bts1) ----
    gemmT(wts1H, wts1L);
    __syncthreads();
#pragma unroll
    for (int mf = 0; mf < 2; ++mf) {
      int chb = wid * 32 + mf * 16 + lg * 4;
      float4 b4 = *(const float4*)(bts1 + chb);
#pragma unroll
      for (int nf = 0; nf < 2; ++nf) {
        int q = nf * 16 + l15;
        float v0 = fmaxf(acc[mf][nf][0] + b4.x, 0.f);
        float v1 = fmaxf(acc[mf][nf][1] + b4.y, 0.f);
        float v2 = fmaxf(acc[mf][nf][2] + b4.z, 0.f);
        float v3 = fmaxf(acc[mf][nf][3] + b4.w, 0.f);
        ushort4 hh, ll;
        split2(v0, hh.x, ll.x); split2(v1, hh.y, ll.y);
        split2(v2, hh.z, ll.z); split2(v3, hh.w, ll.w);
        *(ushort4*)&AS[0][chb >> 3][q][chb & 7] = hh;
        *(ushort4*)&AS[1][chb >> 3][q][chb & 7] = ll;
      }
    }
    __syncthreads();
    // ---- g4: @wts2 + bts2 -> qout (+copies); stage qp=qout+pos if qtmp ----
    gemmT(wts2H, wts2L);
    __syncthreads();
#pragma unroll
    for (int mf = 0; mf < 2; ++mf) {
      int chb = wid * 32 + mf * 16 + lg * 4;
      float4 b4 = *(const float4*)(bts2 + chb);
#pragma unroll
      for (int nf = 0; nf < 2; ++nf) {
        int q = nf * 16 + l15;
        int qg = r0 + q;
        float4 o;
        o.x = acc[mf][nf][0] + b4.x; o.y = acc[mf][nf][1] + b4.y;
        o.z = acc[mf][nf][2] + b4.z; o.w = acc[mf][nf][3] + b4.w;
        if (qg < 10000) {
          size_t go = (size_t)qg * 256 + chb;
          *(float4*)(qout + go) = o;
          if (outA) { *(float4*)(outA + go) = o; *(float4*)(outB + go) = o; }
        }
        if (qtmp) {
          int qc = qg > 9999 ? 9999 : qg;
          float4 pv = *(const float4*)(pos + (size_t)qc * 256 + chb);
          ushort4 hh, ll;
          split2(o.x + pv.x, hh.x, ll.x); split2(o.y + pv.y, hh.y, ll.y);
          split2(o.z + pv.z, hh.z, ll.z); split2(o.w + pv.w, hh.w, ll.w);
          *(ushort4*)&AS[0][chb >> 3][q][chb & 7] = hh;
          *(ushort4*)&AS[1][chb >> 3][q][chb & 7] = ll;
        }
      }
    }
    if (!qtmp) return;
    __syncthreads();
  }

  // ---- g1': qp @ wcat + bcat -> qtmp (288 cols) ----
  {
    int cb, mfw;
    if (wid < 2) { cb = wid * 48; mfw = 3; }
    else { cb = 96 + (wid - 2) * 32; mfw = 2; }
    f32x4 acc2[3][2];
#pragma unroll
    for (int mf = 0; mf < 3; ++mf)
#pragma unroll
      for (int nf = 0; nf < 2; ++nf) acc2[mf][nf] = zed;
#pragma unroll
    for (int ks = 0; ks < 8; ++ks) {
      bf16x8 bqh[2], bql[2];
#pragma unroll
      for (int nf = 0; nf < 2; ++nf) {
        bqh[nf] = *(const bf16x8*)&AS[0][ks * 4 + lk][nf * 16 + l15][0];
        bql[nf] = *(const bf16x8*)&AS[1][ks * 4 + lk][nf * 16 + l15][0];
      }
#pragma unroll
      for (int mf = 0; mf < 3; ++mf) {
        if (mf >= mfw) continue;
        int m = cb + mf * 16 + l15;
        size_t bo = (size_t)m * 256 + ks * 32 + lk * 8;
        bf16x8 ah = *(const bf16x8*)(wcatH + bo);
        bf16x8 al = *(const bf16x8*)(wcatL + bo);
#pragma unroll
        for (int nf = 0; nf < 2; ++nf) {
          acc2[mf][nf] = __builtin_amdgcn_mfma_f32_16x16x32_bf16(ah, bqh[nf], acc2[mf][nf], 0, 0, 0);
          acc2[mf][nf] = __builtin_amdgcn_mfma_f32_16x16x32_bf16(ah, bql[nf], acc2[mf][nf], 0, 0, 0);
          acc2[mf][nf] = __builtin_amdgcn_mfma_f32_16x16x32_bf16(al, bqh[nf], acc2[mf][nf], 0, 0, 0);
        }
      }
    }
#pragma unroll
    for (int mf = 0; mf < 3; ++mf) {
      if (mf >= mfw) continue;
      int chb = cb + mf * 16 + lg * 4;
      float4 b4 = *(const float4*)(bcat + chb);
#pragma unroll
      for (int nf = 0; nf < 2; ++nf) {
        int q = nf * 16 + l15;
        int qg = r0 + q;
        if (qg >= 10000) continue;
        float4 o;
        o.x = acc2[mf][nf][0] + b4.x; o.y = acc2[mf][nf][1] + b4.y;
        o.z = acc2[mf][nf][2] + b4.z; o.w = acc2[mf][nf][3] + b4.w;
        *(float4*)(qtmp + (size_t)qg * 288 + chb) = o;
      }
    }
  }
}

// ---------------- deformable sampling + attention + cam-average -> slots ----------------
__global__ __launch_bounds__(256) void sca_sample(const float* __restrict__ qtmp, const float* __restrict__ V,
                                                  const float* __restrict__ l2i, float* __restrict__ slots)
{
  int b = blockIdx.x;
  int q = (b & 7) * 1250 + (b >> 3);  // XCD-aware: each XCD gets contiguous BEV band
  int t = threadIdx.x;
  int head = t >> 5;
  __shared__ float raw[288];
  __shared__ float attnS[96];
  __shared__ float refx[6][4], refy[6][4];
  __shared__ int mnd[24];
  __shared__ int validn[6];
  __shared__ __align__(16) float w4[576][4];
  __shared__ __align__(16) int o4[576][4];

  raw[t] = qtmp[(size_t)q * 288 + t];
  if (t < 32) raw[256 + t] = qtmp[(size_t)q * 288 + 256 + t];
  if (t >= 32 && t < 56) {
    int tt = t - 32;
    int n = tt >> 2, d = tt & 3;
    const float* Mrow = l2i + n * 16;
    int qx = q % 100, qy = q / 100;
    float X = ((qx + 0.5f) / 100.0f) * 102.4f + (-51.2f);
    float Y = ((qy + 0.5f) / 100.0f) * 102.4f + (-51.2f);
    float zi = (d == 3) ? 7.5f : (0.5f + (float)d * (7.0f / 3.0f));
    float Z = zi + (-5.0f);
    float px = Mrow[0] * X + Mrow[1] * Y + Mrow[2] * Z + Mrow[3];
    float py = Mrow[4] * X + Mrow[5] * Y + Mrow[6] * Z + Mrow[7];
    float pz = Mrow[8] * X + Mrow[9] * Y + Mrow[10] * Z + Mrow[11];
    float dz = fmaxf(pz, 1e-5f);
    float xc = (px / dz) / 704.0f;
    float yc = (py / dz) / 256.0f;
    refx[n][d] = xc; refy[n][d] = yc;
    mnd[n * 4 + d] = (pz > 1e-5f) && (xc > 0.f) && (xc < 1.f) && (yc > 0.f) && (yc < 1.f);
  }
  __syncthreads();
  if (t < 8) {
    float mx = raw[192 + t * 12];
    for (int p = 1; p < 12; ++p) mx = fmaxf(mx, raw[192 + t * 12 + p]);
    float s = 0.f;
    float e[12];
#pragma unroll
    for (int p = 0; p < 12; ++p) { e[p] = __expf(raw[192 + t * 12 + p] - mx); s += e[p]; }
    float inv = 1.f / s;
#pragma unroll
    for (int p = 0; p < 12; ++p) attnS[t * 12 + p] = e[p] * inv;
  } else if (t < 14) {
    int n = t - 8;
    validn[n] = mnd[n * 4] | mnd[n * 4 + 1] | mnd[n * 4 + 2] | mnd[n * 4 + 3];
  }
  __syncthreads();

  int nv = validn[0] + validn[1] + validn[2] + validn[3] + validn[4] + validn[5];
  float invc = 1.f / (float)(nv > 1 ? nv : 1);

  const float WWf[3] = {88.f, 44.f, 22.f}, HHf[3] = {32.f, 16.f, 8.f};
  const int WWi[3] = {88, 44, 22}, STi[3] = {0, 2816, 3520};
  for (int pt = t; pt < 576; pt += 256) {
    int hd = pt & 7;
    int g = pt >> 3;
    int j = g % 12, n = g / 12;
    int l = j >> 2, d = j & 3;
    float wwf = WWf[l], hhf = HHf[l];
    int wwi = WWi[l], st = STi[l];
    float a = attnS[hd * 12 + j] * invc;
    float ox = raw[hd * 24 + l * 8 + d * 2 + 0];
    float oy = raw[hd * 24 + l * 8 + d * 2 + 1];
    float x = refx[n][d] * wwf + ox - 0.5f;
    float y = refy[n][d] * hhf + oy - 0.5f;
    float x0 = floorf(x), y0 = floorf(y);
    float fx = x - x0, fy = y - y0;
    float wx0 = 1.f - fx, wy0 = 1.f - fy;
    float vx0 = (x0 >= 0.f && x0 < wwf) ? 1.f : 0.f;
    float vx1 = (x0 + 1.f >= 0.f && x0 + 1.f < wwf) ? 1.f : 0.f;
    float vy0 = (y0 >= 0.f && y0 < hhf) ? 1.f : 0.f;
    float vy1 = (y0 + 1.f >= 0.f && y0 + 1.f < hhf) ? 1.f : 0.f;
    w4[pt][0] = a * wx0 * wy0 * vx0 * vy0;
    w4[pt][1] = a * fx * wy0 * vx1 * vy0;
    w4[pt][2] = a * wx0 * fy * vx0 * vy1;
    w4[pt][3] = a * fx * fy * vx1 * vy1;
    int ix0 = (int)fminf(fmaxf(x0, 0.f), wwf - 1.f);
    int ix1 = (int)fminf(fmaxf(x0 + 1.f, 0.f), wwf - 1.f);
    int iy0 = (int)fminf(fmaxf(y0, 0.f), hhf - 1.f);
    int iy1 = (int)fminf(fmaxf(y0 + 1.f, 0.f), hhf - 1.f);
    int rA = (st + iy0 * wwi) * 256, rB = (st + iy1 * wwi) * 256;
    o4[pt][0] = rA + ix0 * 256;
    o4[pt][1] = rA + ix1 * 256;
    o4[pt][2] = rB + ix0 * 256;
    o4[pt][3] = rB + ix1 * 256;
  }
  __syncthreads();

  float accv = 0.f;
#pragma unroll
  for (int n = 0; n < 6; ++n) {
    if (!validn[n]) continue;
    const float* Vn = V + (size_t)n * 946176 + t;
    int pb = n * 96 + head;
#pragma unroll
    for (int j = 0; j < 12; ++j) {
      int pt = pb + j * 8;
      float4 w = *reinterpret_cast<const float4*>(&w4[pt][0]);
      int4 o = *reinterpret_cast<const int4*>(&o4[pt][0]);
      accv = fmaf(w.x, Vn[o.x], accv);
      accv = fmaf(w.y, Vn[o.y], accv);
      accv = fmaf(w.z, Vn[o.z], accv);
      accv = fmaf(w.w, Vn[o.w], accv);
    }
  }
  slots[(size_t)q * 256 + t] = accv;
}

extern "C" void kernel_launch(void* const* d_in, const int* in_sizes, int n_in,
                              void* d_out, int out_size, void* d_ws, size_t ws_size,
                              hipStream_t stream)
{
  const float* imgs = (const float*)d_in[0];
  const float* l2i = (const float*)d_in[1];
  const float* bev_query = (const float*)d_in[2];
  const float* bev_pos = (const float*)d_in[3];
  const float* cams = (const float*)d_in[4];
  const float* lev = (const float*)d_in[5];
  const float* wfpn = (const float*)d_in[6];
  const float* bfpn = (const float*)d_in[7];
  const float* wval = (const float*)d_in[8];
  const float* bval = (const float*)d_in[9];
  const float* woff = (const float*)d_in[10];
  const float* boff = (const float*)d_in[11];
  const float* wattn = (const float*)d_in[12];
  const float* battn = (const float*)d_in[13];
  const float* wout = (const float*)d_in[14];
  const float* bout = (const float*)d_in[15];
  const float* wts1 = (const float*)d_in[16];
  const float* bts1 = (const float*)d_in[17];
  const float* wts2 = (const float*)d_in[18];
  const float* bts2 = (const float*)d_in[19];

  float* W = (float*)d_ws;
  size_t off = 0;
  auto alloc = [&](size_t n) { float* p = W + off; off += n; return p; };
  float* v    = alloc((size_t)6 * 3696 * 256);     // 5,677,056
  float* cur1 = alloc((size_t)12 * 256 * 16 * 44); // 2,162,688
  float* cur2 = alloc((size_t)12 * 256 * 8 * 22);  //   540,672
  float* bqA  = alloc(2560000);
  float* bqB  = alloc(2560000);
  float* qtmp = alloc(2880000);
  float* slots = alloc(2560000);
  float* wcatR = alloc(73728);
  float* woutR = alloc(65536);
  float* wts1R = alloc(65536);
  float* wts2R = alloc(65536);
  float* wcombR = alloc(196608);
  float* bcat = alloc(512);
  float* e2 = alloc(4608);
  (void)ws_size; (void)in_sizes; (void)n_in; (void)out_size;

  unsigned short* wcat_h = (unsigned short*)wcatR;   unsigned short* wcat_l = wcat_h + 288 * 256;
  unsigned short* wout_h = (unsigned short*)woutR;   unsigned short* wout_l = wout_h + 65536;
  unsigned short* wts1_h = (unsigned short*)wts1R;   unsigned short* wts1_l = wts1_h + 65536;
  unsigned short* wts2_h = (unsigned short*)wts2R;   unsigned short* wts2_l = wts2_h + 65536;
  unsigned short* wcomb_h = (unsigned short*)wcombR; unsigned short* wcomb_l = wcomb_h + 3 * 65536;

  float* OUT = (float*)d_out;

  // precompute
  pool2x2<<<8448, 256, 0, stream>>>(imgs, cur1, 16, 44, 2162688);
  pool2x2<<<2112, 256, 0, stream>>>(cur1, cur2, 8, 22, 540672);
  prep<<<1842, 256, 0, stream>>>(woff, boff, wattn, battn, wout, wts1, wts2, wfpn, wval,
                                 cams, lev, bfpn, bval,
                                 wcat_h, wcat_l, bcat, wout_h, wout_l, wts1_h, wts1_l,
                                 wts2_h, wts2_l, wcomb_h, wcomb_l, e2);

  // initial qtmp = (bev_query+pos)@wcat + bcat
  fused_iter<<<313, 512, 0, stream>>>(nullptr, bev_query, bev_pos,
      wout_h, wout_l, wts1_h, wts1_l, wts2_h, wts2_l, wcat_h, wcat_l,
      bout, bts1, bts2, bcat, bqA, nullptr, nullptr, qtmp, 1);

  // value b0
  value_fused<<<dim3(116, 6), 512, 0, stream>>>(imgs, cur1, cur2, wcomb_h, wcomb_l, e2, v);

  // iter 1
  sca_sample<<<10000, 256, 0, stream>>>(qtmp, v, l2i, slots);
  fused_iter<<<313, 512, 0, stream>>>(slots, bev_query, bev_pos,
      wout_h, wout_l, wts1_h, wts1_l, wts2_h, wts2_l, wcat_h, wcat_l,
      bout, bts1, bts2, bcat, bqA, nullptr, nullptr, qtmp, 0);
  // iter 2 -> ego (bqB + d_out groups 0,1)
  sca_sample<<<10000, 256, 0, stream>>>(qtmp, v, l2i, slots);
  fused_iter<<<313, 512, 0, stream>>>(slots, bqA, bev_pos,
      wout_h, wout_l, wts1_h, wts1_l, wts2_h, wts2_l, wcat_h, wcat_l,
      bout, bts1, bts2, bcat, bqB, OUT, OUT + 2560000, qtmp, 0);

  // value b1
  value_fused<<<dim3(116, 6), 512, 0, stream>>>(imgs + (size_t)4325376, cur1 + (size_t)1081344,
                                                cur2 + (size_t)270336, wcomb_h, wcomb_l, e2, v);
  // iter 3 -> nb (directly into d_out)
  sca_sample<<<10000, 256, 0, stream>>>(qtmp, v, l2i + 96, slots);
  fused_iter<<<313, 512, 0, stream>>>(slots, bqB, bev_pos,
      wout_h, wout_l, wts1_h, wts1_l, wts2_h, wts2_l, wcat_h, wcat_l,
      bout, bts1, bts2, bcat, OUT + 5120000, nullptr, nullptr, nullptr, 0);
}

// Round 5
// 411.701 us; speedup vs baseline: 2.6399x; 1.3422x over previous
//
#include <hip/hip_runtime.h>
#include <math.h>

typedef __attribute__((ext_vector_type(8))) short bf16x8;
typedef __attribute__((ext_vector_type(4))) float f32x4;

__device__ __forceinline__ unsigned short f2bf(float x) {
  union { float f; unsigned int u; } v; v.f = x;
  unsigned int r = v.u + 0x7fffu + ((v.u >> 16) & 1u);
  return (unsigned short)(r >> 16);
}
__device__ __forceinline__ float bf2f(unsigned short b) {
  union { unsigned int u; float f; } v; v.u = ((unsigned int)b) << 16; return v.f;
}
__device__ __forceinline__ void split2(float x, unsigned short& h, unsigned short& l) {
  h = f2bf(x);
  l = f2bf(x - bf2f(h));
}

// ---------------- pooling (2x2 mean) ----------------
__global__ __launch_bounds__(256) void pool2x2(const float* __restrict__ in, float* __restrict__ out,
                                               int h, int w, int total)
{
  int i = blockIdx.x * 256 + threadIdx.x;
  if (i >= total) return;
  int x = i % w; int r = i / w; int y = r % h; int ci = r / h;
  const float* p = in + (size_t)ci * (4 * h * w) + (size_t)(2 * y) * (2 * w) + 2 * x;
  out[i] = (p[0] + p[1] + p[2 * w] + p[2 * w + 1]) * 0.25f;
}

// ---------------- merged weight prep ----------------
__global__ __launch_bounds__(256) void prep(
    const float* __restrict__ wo, const float* __restrict__ bo,
    const float* __restrict__ wa, const float* __restrict__ ba,
    const float* __restrict__ wout, const float* __restrict__ wts1, const float* __restrict__ wts2,
    const float* __restrict__ wfpn, const float* __restrict__ wval,
    const float* __restrict__ cams, const float* __restrict__ lev,
    const float* __restrict__ bfpn, const float* __restrict__ bval,
    unsigned short* __restrict__ wcatH, unsigned short* __restrict__ wcatL, float* __restrict__ bcat,
    unsigned short* __restrict__ woutH, unsigned short* __restrict__ woutL,
    unsigned short* __restrict__ wts1H, unsigned short* __restrict__ wts1L,
    unsigned short* __restrict__ wts2H, unsigned short* __restrict__ wts2L,
    unsigned short* __restrict__ wcombH, unsigned short* __restrict__ wcombL,
    float* __restrict__ e2)
{
  int bb = blockIdx.x, t = threadIdx.x;
  if (bb < 768) { // wcombT[l][n][k] = (wfpn[l]@wval)^T split
    int l = bb >> 8, i = bb & 255, j = t;
    const float* a = wfpn + ((size_t)l * 256 + i) * 256;
    float acc = 0.f;
    for (int k = 0; k < 256; ++k) acc = fmaf(a[k], wval[(size_t)k * 256 + j], acc);
    unsigned short h, lo; split2(acc, h, lo);
    size_t o = ((size_t)l * 256 + j) * 256 + i;
    wcombH[o] = h; wcombL[o] = lo;
  } else if (bb < 1056) { // wcatT (288,256) split + bcat
    int i = (bb - 768) * 256 + t;
    int c = i >> 8, k = i & 255;
    float v = (c < 192) ? wo[k * 192 + c] : wa[k * 96 + (c - 192)];
    unsigned short h, l; split2(v, h, l);
    wcatH[i] = h; wcatL[i] = l;
    if (i < 288) bcat[i] = (i < 192) ? bo[i] : ba[i - 192];
  } else if (bb < 1824) { // conv_w for wout/wts1/wts2
    int sel = (bb - 1056) >> 8;
    int i = ((bb - 1056) & 255) * 256 + t;
    int nn = i >> 8, k = i & 255;
    const float* B = (sel == 0) ? wout : (sel == 1) ? wts1 : wts2;
    unsigned short* H = (sel == 0) ? woutH : (sel == 1) ? wts1H : wts2H;
    unsigned short* L = (sel == 0) ? woutL : (sel == 1) ? wts1L : wts2L;
    float v = B[(size_t)k * 256 + nn];
    unsigned short h, l; split2(v, h, l);
    H[i] = h; L[i] = l;
  } else { // e2
    int e = bb - 1824;
    int n = e / 3, l = e % 3, j = t;
    float acc = bval[j];
    for (int k = 0; k < 256; ++k) {
      float s = cams[n * 256 + k] + lev[l * 256 + k] + bfpn[l * 256 + k];
      acc = fmaf(s, wval[(size_t)k * 256 + j], acc);
    }
    e2[(size_t)e * 256 + j] = acc;
  }
}

// ---------------- fused value kernel: transpose+split imgs tile, GEMM with wcomb, write V ----------------
__global__ __launch_bounds__(512) void value_fused(
    const float* __restrict__ img0, const float* __restrict__ cur1, const float* __restrict__ cur2,
    const unsigned short* __restrict__ wcH, const unsigned short* __restrict__ wcL,
    const float* __restrict__ e2, float* __restrict__ V)
{
  __shared__ __align__(16) unsigned short AS[2][32][32][8];
  int t = threadIdx.x, wid = t >> 6, lane = t & 63, l15 = lane & 15, lk = lane >> 4;
  int bx = blockIdx.x, cam = blockIdx.y;
  int level, tb, hw; const float* src;
  if (bx < 88)       { level = 0; tb = bx;       hw = 2816; src = img0; }
  else if (bx < 110) { level = 1; tb = bx - 88;  hw = 704;  src = cur1; }
  else               { level = 2; tb = bx - 110; hw = 176;  src = cur2; }
  int p0 = tb * 32;
  const int LST[3] = {0, 2816, 3520};
  src += (size_t)cam * 256 * hw;

  { // stage: (k-major) -> LDS (pos, k) hi/lo
    int f4g = t & 7, kb = t >> 3;  // kb 0..63
    bool full = (p0 + 32 <= hw);
#pragma unroll
    for (int j = 0; j < 4; ++j) {
      int k = kb + j * 64;
      const float* row = src + (size_t)k * hw;
      int p = p0 + 4 * f4g;
      float4 v;
      if (full) v = *(const float4*)(row + p);
      else {
        v.x = (p < hw) ? row[p] : 0.f;     v.y = (p + 1 < hw) ? row[p + 1] : 0.f;
        v.z = (p + 2 < hw) ? row[p + 2] : 0.f; v.w = (p + 3 < hw) ? row[p + 3] : 0.f;
      }
      int ch = k >> 3, ko = k & 7;
      unsigned short h, l;
      split2(v.x, h, l); AS[0][ch][4 * f4g + 0][ko] = h; AS[1][ch][4 * f4g + 0][ko] = l;
      split2(v.y, h, l); AS[0][ch][4 * f4g + 1][ko] = h; AS[1][ch][4 * f4g + 1][ko] = l;
      split2(v.z, h, l); AS[0][ch][4 * f4g + 2][ko] = h; AS[1][ch][4 * f4g + 2][ko] = l;
      split2(v.w, h, l); AS[0][ch][4 * f4g + 3][ko] = h; AS[1][ch][4 * f4g + 3][ko] = l;
    }
  }
  __syncthreads();

  const unsigned short* AH = wcH + (size_t)level * 65536;
  const unsigned short* AL = wcL + (size_t)level * 65536;
  f32x4 zed = {0.f, 0.f, 0.f, 0.f};
  f32x4 acc[2][2];
#pragma unroll
  for (int mf = 0; mf < 2; ++mf)
#pragma unroll
    for (int nf = 0; nf < 2; ++nf) acc[mf][nf] = zed;
#pragma unroll
  for (int ks = 0; ks < 8; ++ks) {
    bf16x8 bqh[2], bql[2];
#pragma unroll
    for (int nf = 0; nf < 2; ++nf) {
      bqh[nf] = *(const bf16x8*)&AS[0][ks * 4 + lk][nf * 16 + l15][0];
      bql[nf] = *(const bf16x8*)&AS[1][ks * 4 + lk][nf * 16 + l15][0];
    }
#pragma unroll
    for (int mf = 0; mf < 2; ++mf) {
      int m = wid * 32 + mf * 16 + l15;
      size_t bo = (size_t)m * 256 + ks * 32 + lk * 8;
      bf16x8 ah = *(const bf16x8*)(AH + bo);
      bf16x8 al = *(const bf16x8*)(AL + bo);
#pragma unroll
      for (int nf = 0; nf < 2; ++nf) {
        acc[mf][nf] = __builtin_amdgcn_mfma_f32_16x16x32_bf16(ah, bqh[nf], acc[mf][nf], 0, 0, 0);
        acc[mf][nf] = __builtin_amdgcn_mfma_f32_16x16x32_bf16(ah, bql[nf], acc[mf][nf], 0, 0, 0);
        acc[mf][nf] = __builtin_amdgcn_mfma_f32_16x16x32_bf16(al, bqh[nf], acc[mf][nf], 0, 0, 0);
      }
    }
  }
  // epilogue: row=out-channel, col=pos
  const float* bias = e2 + (size_t)(cam * 3 + level) * 256;
  float* Vb = V + ((size_t)cam * 3696 + LST[level] + p0) * 256;
  int lg = lane >> 4;
#pragma unroll
  for (int mf = 0; mf < 2; ++mf) {
    int chb = wid * 32 + mf * 16 + lg * 4;
    float4 b4 = *(const float4*)(bias + chb);
#pragma unroll
    for (int nf = 0; nf < 2; ++nf) {
      int q = nf * 16 + l15;
      if (p0 + q >= hw) continue;
      float4 o;
      o.x = acc[mf][nf][0] + b4.x; o.y = acc[mf][nf][1] + b4.y;
      o.z = acc[mf][nf][2] + b4.z; o.w = acc[mf][nf][3] + b4.w;
      *(float4*)(Vb + (size_t)q * 256 + chb) = o;
    }
  }
}

// ---------------- fused iteration kernel (512 threads, 8 waves) ----------------
__global__ __launch_bounds__(512) void fused_iter(
    const float* __restrict__ slots, const float* __restrict__ qin, const float* __restrict__ pos,
    const unsigned short* __restrict__ woutH, const unsigned short* __restrict__ woutL,
    const unsigned short* __restrict__ wts1H, const unsigned short* __restrict__ wts1L,
    const unsigned short* __restrict__ wts2H, const unsigned short* __restrict__ wts2L,
    const unsigned short* __restrict__ wcatH, const unsigned short* __restrict__ wcatL,
    const float* __restrict__ bout, const float* __restrict__ bts1,
    const float* __restrict__ bts2, const float* __restrict__ bcat,
    float* __restrict__ qout, float* __restrict__ outA, float* __restrict__ outB,
    float* __restrict__ qtmp, int init)
{
  __shared__ __align__(16) unsigned short AS[2][32][32][8];
  int t = threadIdx.x, wid = t >> 6, lane = t & 63, l15 = lane & 15, lk = lane >> 4;
  int lg = lk;
  int r0 = blockIdx.x * 32;
  int rl = t & 31;
  int rg = r0 + rl; int rc = rg > 9999 ? 9999 : rg;

  // ---- phase 0: stage B-side (queries) ----
  {
    int cb2 = (t >> 5) * 2;
    const float* base = (init ? qin : slots) + (size_t)rc * 256;
    const float* pbase = pos + (size_t)rc * 256;
#pragma unroll
    for (int j = 0; j < 2; ++j) {
      int ch = cb2 + j, k0 = ch * 8;
      float4 a0 = *(const float4*)(base + k0);
      float4 a1 = *(const float4*)(base + k0 + 4);
      if (init) {
        float4 p0v = *(const float4*)(pbase + k0);
        float4 p1v = *(const float4*)(pbase + k0 + 4);
        a0.x += p0v.x; a0.y += p0v.y; a0.z += p0v.z; a0.w += p0v.w;
        a1.x += p1v.x; a1.y += p1v.y; a1.z += p1v.z; a1.w += p1v.w;
      }
      bf16x8 hv, lv; unsigned short h, l;
      split2(a0.x, h, l); hv[0] = (short)h; lv[0] = (short)l;
      split2(a0.y, h, l); hv[1] = (short)h; lv[1] = (short)l;
      split2(a0.z, h, l); hv[2] = (short)h; lv[2] = (short)l;
      split2(a0.w, h, l); hv[3] = (short)h; lv[3] = (short)l;
      split2(a1.x, h, l); hv[4] = (short)h; lv[4] = (short)l;
      split2(a1.y, h, l); hv[5] = (short)h; lv[5] = (short)l;
      split2(a1.z, h, l); hv[6] = (short)h; lv[6] = (short)l;
      split2(a1.w, h, l); hv[7] = (short)h; lv[7] = (short)l;
      *(bf16x8*)&AS[0][ch][rl][0] = hv;
      *(bf16x8*)&AS[1][ch][rl][0] = lv;
    }
  }
  __syncthreads();

  f32x4 zed = {0.f, 0.f, 0.f, 0.f};
  f32x4 acc[2][2];

  auto gemmT = [&](const unsigned short* AH, const unsigned short* AL) {
#pragma unroll
    for (int mf = 0; mf < 2; ++mf)
#pragma unroll
      for (int nf = 0; nf < 2; ++nf) acc[mf][nf] = zed;
#pragma unroll
    for (int ks = 0; ks < 8; ++ks) {
      bf16x8 bqh[2], bql[2];
#pragma unroll
      for (int nf = 0; nf < 2; ++nf) {
        bqh[nf] = *(const bf16x8*)&AS[0][ks * 4 + lk][nf * 16 + l15][0];
        bql[nf] = *(const bf16x8*)&AS[1][ks * 4 + lk][nf * 16 + l15][0];
      }
#pragma unroll
      for (int mf = 0; mf < 2; ++mf) {
        int m = wid * 32 + mf * 16 + l15;
        size_t bo = (size_t)m * 256 + ks * 32 + lk * 8;
        bf16x8 ah = *(const bf16x8*)(AH + bo);
        bf16x8 al = *(const bf16x8*)(AL + bo);
#pragma unroll
        for (int nf = 0; nf < 2; ++nf) {
          acc[mf][nf] = __builtin_amdgcn_mfma_f32_16x16x32_bf16(ah, bqh[nf], acc[mf][nf], 0, 0, 0);
          acc[mf][nf] = __builtin_amdgcn_mfma_f32_16x16x32_bf16(ah, bql[nf], acc[mf][nf], 0, 0, 0);
          acc[mf][nf] = __builtin_amdgcn_mfma_f32_16x16x32_bf16(al, bqh[nf], acc[mf][nf], 0, 0, 0);
        }
      }
    }
  };

  if (!init) {
    // ---- g2: slots@wout + bout + qin ----
    gemmT(woutH, woutL);
    __syncthreads();
#pragma unroll
    for (int mf = 0; mf < 2; ++mf) {
      int chb = wid * 32 + mf * 16 + lg * 4;
      float4 b4 = *(const float4*)(bout + chb);
#pragma unroll
      for (int nf = 0; nf < 2; ++nf) {
        int q = nf * 16 + l15;
        int qg = r0 + q; int qc = qg > 9999 ? 9999 : qg;
        float4 rr = *(const float4*)(qin + (size_t)qc * 256 + chb);
        float v0 = acc[mf][nf][0] + b4.x + rr.x;
        float v1 = acc[mf][nf][1] + b4.y + rr.y;
        float v2 = acc[mf][nf][2] + b4.z + rr.z;
        float v3 = acc[mf][nf][3] + b4.w + rr.w;
        ushort4 hh, ll;
        split2(v0, hh.x, ll.x); split2(v1, hh.y, ll.y);
        split2(v2, hh.z, ll.z); split2(v3, hh.w, ll.w);
        *(ushort4*)&AS[0][chb >> 3][q][chb & 7] = hh;
        *(ushort4*)&AS[1][chb >> 3][q][chb & 7] = ll;
      }
    }
    __syncthreads();
    // ---- g3: relu(@wts1 + bts1) ----
    gemmT(wts1H, wts1L);
    __syncthreads();
#pragma unroll
    for (int mf = 0; mf < 2; ++mf) {
      int chb = wid * 32 + mf * 16 + lg * 4;
      float4 b4 = *(const float4*)(bts1 + chb);
#pragma unroll
      for (int nf = 0; nf < 2; ++nf) {
        int q = nf * 16 + l15;
        float v0 = fmaxf(acc[mf][nf][0] + b4.x, 0.f);
        float v1 = fmaxf(acc[mf][nf][1] + b4.y, 0.f);
        float v2 = fmaxf(acc[mf][nf][2] + b4.z, 0.f);
        float v3 = fmaxf(acc[mf][nf][3] + b4.w, 0.f);
        ushort4 hh, ll;
        split2(v0, hh.x, ll.x); split2(v1, hh.y, ll.y);
        split2(v2, hh.z, ll.z); split2(v3, hh.w, ll.w);
        *(ushort4*)&AS[0][chb >> 3][q][chb & 7] = hh;
        *(ushort4*)&AS[1][chb >> 3][q][chb & 7] = ll;
      }
    }
    __syncthreads();
    // ---- g4: @wts2 + bts2 -> qout (+copies); stage qp=qout+pos if qtmp ----
    gemmT(wts2H, wts2L);
    __syncthreads();
#pragma unroll
    for (int mf = 0; mf < 2; ++mf) {
      int chb = wid * 32 + mf * 16 + lg * 4;
      float4 b4 = *(const float4*)(bts2 + chb);
#pragma unroll
      for (int nf = 0; nf < 2; ++nf) {
        int q = nf * 16 + l15;
        int qg = r0 + q;
        float4 o;
        o.x = acc[mf][nf][0] + b4.x; o.y = acc[mf][nf][1] + b4.y;
        o.z = acc[mf][nf][2] + b4.z; o.w = acc[mf][nf][3] + b4.w;
        if (qg < 10000) {
          size_t go = (size_t)qg * 256 + chb;
          *(float4*)(qout + go) = o;
          if (outA) { *(float4*)(outA + go) = o; *(float4*)(outB + go) = o; }
        }
        if (qtmp) {
          int qc = qg > 9999 ? 9999 : qg;
          float4 pv = *(const float4*)(pos + (size_t)qc * 256 + chb);
          ushort4 hh, ll;
          split2(o.x + pv.x, hh.x, ll.x); split2(o.y + pv.y, hh.y, ll.y);
          split2(o.z + pv.z, hh.z, ll.z); split2(o.w + pv.w, hh.w, ll.w);
          *(ushort4*)&AS[0][chb >> 3][q][chb & 7] = hh;
          *(ushort4*)&AS[1][chb >> 3][q][chb & 7] = ll;
        }
      }
    }
    if (!qtmp) return;
    __syncthreads();
  }

  // ---- g1': qp @ wcat + bcat -> qtmp (288 cols) ----
  {
    int cb, mfw;
    if (wid < 2) { cb = wid * 48; mfw = 3; }
    else { cb = 96 + (wid - 2) * 32; mfw = 2; }
    f32x4 acc2[3][2];
#pragma unroll
    for (int mf = 0; mf < 3; ++mf)
#pragma unroll
      for (int nf = 0; nf < 2; ++nf) acc2[mf][nf] = zed;
#pragma unroll
    for (int ks = 0; ks < 8; ++ks) {
      bf16x8 bqh[2], bql[2];
#pragma unroll
      for (int nf = 0; nf < 2; ++nf) {
        bqh[nf] = *(const bf16x8*)&AS[0][ks * 4 + lk][nf * 16 + l15][0];
        bql[nf] = *(const bf16x8*)&AS[1][ks * 4 + lk][nf * 16 + l15][0];
      }
#pragma unroll
      for (int mf = 0; mf < 3; ++mf) {
        if (mf >= mfw) continue;
        int m = cb + mf * 16 + l15;
        size_t bo = (size_t)m * 256 + ks * 32 + lk * 8;
        bf16x8 ah = *(const bf16x8*)(wcatH + bo);
        bf16x8 al = *(const bf16x8*)(wcatL + bo);
#pragma unroll
        for (int nf = 0; nf < 2; ++nf) {
          acc2[mf][nf] = __builtin_amdgcn_mfma_f32_16x16x32_bf16(ah, bqh[nf], acc2[mf][nf], 0, 0, 0);
          acc2[mf][nf] = __builtin_amdgcn_mfma_f32_16x16x32_bf16(ah, bql[nf], acc2[mf][nf], 0, 0, 0);
          acc2[mf][nf] = __builtin_amdgcn_mfma_f32_16x16x32_bf16(al, bqh[nf], acc2[mf][nf], 0, 0, 0);
        }
      }
    }
#pragma unroll
    for (int mf = 0; mf < 3; ++mf) {
      if (mf >= mfw) continue;
      int chb = cb + mf * 16 + lg * 4;
      float4 b4 = *(const float4*)(bcat + chb);
#pragma unroll
      for (int nf = 0; nf < 2; ++nf) {
        int q = nf * 16 + l15;
        int qg = r0 + q;
        if (qg >= 10000) continue;
        float4 o;
        o.x = acc2[mf][nf][0] + b4.x; o.y = acc2[mf][nf][1] + b4.y;
        o.z = acc2[mf][nf][2] + b4.z; o.w = acc2[mf][nf][3] + b4.w;
        *(float4*)(qtmp + (size_t)qg * 288 + chb) = o;
      }
    }
  }
}

// ---------------- deformable sampling + attention + cam-average -> slots ----------------
__global__ __launch_bounds__(256) void sca_sample(const float* __restrict__ qtmp, const float* __restrict__ V,
                                                  const float* __restrict__ l2i, float* __restrict__ slots)
{
  int b = blockIdx.x;
  int q = (b & 7) * 1250 + (b >> 3);  // XCD-aware: each XCD gets contiguous BEV band
  int t = threadIdx.x;
  int head = t >> 5;
  __shared__ float raw[288];
  __shared__ float attnS[96];
  __shared__ float refx[6][4], refy[6][4];
  __shared__ int mnd[24];
  __shared__ int validn[6];
  __shared__ __align__(16) float w4[576][4];
  __shared__ __align__(16) int o4[576][4];

  raw[t] = qtmp[(size_t)q * 288 + t];
  if (t < 32) raw[256 + t] = qtmp[(size_t)q * 288 + 256 + t];
  if (t >= 32 && t < 56) {
    int tt = t - 32;
    int n = tt >> 2, d = tt & 3;
    const float* Mrow = l2i + n * 16;
    int qx = q % 100, qy = q / 100;
    float X = ((qx + 0.5f) / 100.0f) * 102.4f + (-51.2f);
    float Y = ((qy + 0.5f) / 100.0f) * 102.4f + (-51.2f);
    float zi = (d == 3) ? 7.5f : (0.5f + (float)d * (7.0f / 3.0f));
    float Z = zi + (-5.0f);
    float px = Mrow[0] * X + Mrow[1] * Y + Mrow[2] * Z + Mrow[3];
    float py = Mrow[4] * X + Mrow[5] * Y + Mrow[6] * Z + Mrow[7];
    float pz = Mrow[8] * X + Mrow[9] * Y + Mrow[10] * Z + Mrow[11];
    float dz = fmaxf(pz, 1e-5f);
    float xc = (px / dz) / 704.0f;
    float yc = (py / dz) / 256.0f;
    refx[n][d] = xc; refy[n][d] = yc;
    mnd[n * 4 + d] = (pz > 1e-5f) && (xc > 0.f) && (xc < 1.f) && (yc > 0.f) && (yc < 1.f);
  }
  __syncthreads();
  if (t < 8) {
    float mx = raw[192 + t * 12];
    for (int p = 1; p < 12; ++p) mx = fmaxf(mx, raw[192 + t * 12 + p]);
    float s = 0.f;
    float e[12];
#pragma unroll
    for (int p = 0; p < 12; ++p) { e[p] = __expf(raw[192 + t * 12 + p] - mx); s += e[p]; }
    float inv = 1.f / s;
#pragma unroll
    for (int p = 0; p < 12; ++p) attnS[t * 12 + p] = e[p] * inv;
  } else if (t < 14) {
    int n = t - 8;
    validn[n] = mnd[n * 4] | mnd[n * 4 + 1] | mnd[n * 4 + 2] | mnd[n * 4 + 3];
  }
  __syncthreads();

  int nv = validn[0] + validn[1] + validn[2] + validn[3] + validn[4] + validn[5];
  float invc = 1.f / (float)(nv > 1 ? nv : 1);

  const float WWf[3] = {88.f, 44.f, 22.f}, HHf[3] = {32.f, 16.f, 8.f};
  const int WWi[3] = {88, 44, 22}, STi[3] = {0, 2816, 3520};
  for (int pt = t; pt < 576; pt += 256) {
    int hd = pt & 7;
    int g = pt >> 3;
    int j = g % 12, n = g / 12;
    int l = j >> 2, d = j & 3;
    float wwf = WWf[l], hhf = HHf[l];
    int wwi = WWi[l], st = STi[l];
    float a = attnS[hd * 12 + j] * invc;
    float ox = raw[hd * 24 + l * 8 + d * 2 + 0];
    float oy = raw[hd * 24 + l * 8 + d * 2 + 1];
    float x = refx[n][d] * wwf + ox - 0.5f;
    float y = refy[n][d] * hhf + oy - 0.5f;
    float x0 = floorf(x), y0 = floorf(y);
    float fx = x - x0, fy = y - y0;
    float wx0 = 1.f - fx, wy0 = 1.f - fy;
    float vx0 = (x0 >= 0.f && x0 < wwf) ? 1.f : 0.f;
    float vx1 = (x0 + 1.f >= 0.f && x0 + 1.f < wwf) ? 1.f : 0.f;
    float vy0 = (y0 >= 0.f && y0 < hhf) ? 1.f : 0.f;
    float vy1 = (y0 + 1.f >= 0.f && y0 + 1.f < hhf) ? 1.f : 0.f;
    w4[pt][0] = a * wx0 * wy0 * vx0 * vy0;
    w4[pt][1] = a * fx * wy0 * vx1 * vy0;
    w4[pt][2] = a * wx0 * fy * vx0 * vy1;
    w4[pt][3] = a * fx * fy * vx1 * vy1;
    int ix0 = (int)fminf(fmaxf(x0, 0.f), wwf - 1.f);
    int ix1 = (int)fminf(fmaxf(x0 + 1.f, 0.f), wwf - 1.f);
    int iy0 = (int)fminf(fmaxf(y0, 0.f), hhf - 1.f);
    int iy1 = (int)fminf(fmaxf(y0 + 1.f, 0.f), hhf - 1.f);
    int rA = (st + iy0 * wwi) * 256, rB = (st + iy1 * wwi) * 256;
    o4[pt][0] = rA + ix0 * 256;
    o4[pt][1] = rA + ix1 * 256;
    o4[pt][2] = rB + ix0 * 256;
    o4[pt][3] = rB + ix1 * 256;
  }
  __syncthreads();

  // main gather loop: per valid cam, batch-issue all 48 tap loads into registers
  // (deep vmcnt pipeline), then FMA. Two accumulators to shorten the chain.
  float acc0 = 0.f, acc1 = 0.f;
#pragma unroll
  for (int n = 0; n < 6; ++n) {
    if (!validn[n]) continue;
    const float* Vn = V + (size_t)n * 946176 + t;
    int pb = n * 96 + head;
    float va[48];
#pragma unroll
    for (int j = 0; j < 12; ++j) {
      int4 o = *reinterpret_cast<const int4*>(&o4[pb + j * 8][0]);
      va[4 * j + 0] = Vn[o.x];
      va[4 * j + 1] = Vn[o.y];
      va[4 * j + 2] = Vn[o.z];
      va[4 * j + 3] = Vn[o.w];
    }
#pragma unroll
    for (int j = 0; j < 12; ++j) {
      float4 w = *reinterpret_cast<const float4*>(&w4[pb + j * 8][0]);
      acc0 = fmaf(w.x, va[4 * j + 0], acc0);
      acc1 = fmaf(w.y, va[4 * j + 1], acc1);
      acc0 = fmaf(w.z, va[4 * j + 2], acc0);
      acc1 = fmaf(w.w, va[4 * j + 3], acc1);
    }
  }
  slots[(size_t)q * 256 + t] = acc0 + acc1;
}

extern "C" void kernel_launch(void* const* d_in, const int* in_sizes, int n_in,
                              void* d_out, int out_size, void* d_ws, size_t ws_size,
                              hipStream_t stream)
{
  const float* imgs = (const float*)d_in[0];
  const float* l2i = (const float*)d_in[1];
  const float* bev_query = (const float*)d_in[2];
  const float* bev_pos = (const float*)d_in[3];
  const float* cams = (const float*)d_in[4];
  const float* lev = (const float*)d_in[5];
  const float* wfpn = (const float*)d_in[6];
  const float* bfpn = (const float*)d_in[7];
  const float* wval = (const float*)d_in[8];
  const float* bval = (const float*)d_in[9];
  const float* woff = (const float*)d_in[10];
  const float* boff = (const float*)d_in[11];
  const float* wattn = (const float*)d_in[12];
  const float* battn = (const float*)d_in[13];
  const float* wout = (const float*)d_in[14];
  const float* bout = (const float*)d_in[15];
  const float* wts1 = (const float*)d_in[16];
  const float* bts1 = (const float*)d_in[17];
  const float* wts2 = (const float*)d_in[18];
  const float* bts2 = (const float*)d_in[19];

  float* W = (float*)d_ws;
  size_t off = 0;
  auto alloc = [&](size_t n) { float* p = W + off; off += n; return p; };
  float* v    = alloc((size_t)6 * 3696 * 256);     // 5,677,056
  float* cur1 = alloc((size_t)12 * 256 * 16 * 44); // 2,162,688
  float* cur2 = alloc((size_t)12 * 256 * 8 * 22);  //   540,672
  float* bqA  = alloc(2560000);
  float* bqB  = alloc(2560000);
  float* qtmp = alloc(2880000);
  float* slots = alloc(2560000);
  float* wcatR = alloc(73728);
  float* woutR = alloc(65536);
  float* wts1R = alloc(65536);
  float* wts2R = alloc(65536);
  float* wcombR = alloc(196608);
  float* bcat = alloc(512);
  float* e2 = alloc(4608);
  (void)ws_size; (void)in_sizes; (void)n_in; (void)out_size;

  unsigned short* wcat_h = (unsigned short*)wcatR;   unsigned short* wcat_l = wcat_h + 288 * 256;
  unsigned short* wout_h = (unsigned short*)woutR;   unsigned short* wout_l = wout_h + 65536;
  unsigned short* wts1_h = (unsigned short*)wts1R;   unsigned short* wts1_l = wts1_h + 65536;
  unsigned short* wts2_h = (unsigned short*)wts2R;   unsigned short* wts2_l = wts2_h + 65536;
  unsigned short* wcomb_h = (unsigned short*)wcombR; unsigned short* wcomb_l = wcomb_h + 3 * 65536;

  float* OUT = (float*)d_out;

  // precompute
  pool2x2<<<8448, 256, 0, stream>>>(imgs, cur1, 16, 44, 2162688);
  pool2x2<<<2112, 256, 0, stream>>>(cur1, cur2, 8, 22, 540672);
  prep<<<1842, 256, 0, stream>>>(woff, boff, wattn, battn, wout, wts1, wts2, wfpn, wval,
                                 cams, lev, bfpn, bval,
                                 wcat_h, wcat_l, bcat, wout_h, wout_l, wts1_h, wts1_l,
                                 wts2_h, wts2_l, wcomb_h, wcomb_l, e2);

  // initial qtmp = (bev_query+pos)@wcat + bcat
  fused_iter<<<313, 512, 0, stream>>>(nullptr, bev_query, bev_pos,
      wout_h, wout_l, wts1_h, wts1_l, wts2_h, wts2_l, wcat_h, wcat_l,
      bout, bts1, bts2, bcat, bqA, nullptr, nullptr, qtmp, 1);

  // value b0
  value_fused<<<dim3(116, 6), 512, 0, stream>>>(imgs, cur1, cur2, wcomb_h, wcomb_l, e2, v);

  // iter 1
  sca_sample<<<10000, 256, 0, stream>>>(qtmp, v, l2i, slots);
  fused_iter<<<313, 512, 0, stream>>>(slots, bev_query, bev_pos,
      wout_h, wout_l, wts1_h, wts1_l, wts2_h, wts2_l, wcat_h, wcat_l,
      bout, bts1, bts2, bcat, bqA, nullptr, nullptr, qtmp, 0);
  // iter 2 -> ego (bqB + d_out groups 0,1)
  sca_sample<<<10000, 256, 0, stream>>>(qtmp, v, l2i, slots);
  fused_iter<<<313, 512, 0, stream>>>(slots, bqA, bev_pos,
      wout_h, wout_l, wts1_h, wts1_l, wts2_h, wts2_l, wcat_h, wcat_l,
      bout, bts1, bts2, bcat, bqB, OUT, OUT + 2560000, qtmp, 0);

  // value b1
  value_fused<<<dim3(116, 6), 512, 0, stream>>>(imgs + (size_t)4325376, cur1 + (size_t)1081344,
                                                cur2 + (size_t)270336, wcomb_h, wcomb_l, e2, v);
  // iter 3 -> nb (directly into d_out)
  sca_sample<<<10000, 256, 0, stream>>>(qtmp, v, l2i + 96, slots);
  fused_iter<<<313, 512, 0, stream>>>(slots, bqB, bev_pos,
      wout_h, wout_l, wts1_h, wts1_l, wts2_h, wts2_l, wcat_h, wcat_l,
      bout, bts1, bts2, bcat, OUT + 5120000, nullptr, nullptr, nullptr, 0);
}